// Round 1
// baseline (8559.834 us; speedup 1.0000x reference)
//
#include <hip/hip_runtime.h>

#define M_NODES 100000
#define DIM 128
#define N_EDGES_TOT 1600000

// ---------------------------------------------------------------------------
// Zero a small buffer (avoid hipMemsetAsync to be 100% graph-capture safe).
__global__ void k_zero(float* p, int n) {
    int i = blockIdx.x * 256 + threadIdx.x;
    if (i < n) p[i] = 0.f;
}

// ---------------------------------------------------------------------------
// agg[i] = BNrelu(h[i]) elementwise (or plain copy when scale==nullptr).
// n4 = number of float4 elements.
__global__ void k_init(const float* __restrict__ h,
                       const float* __restrict__ scale,
                       const float* __restrict__ shift,
                       float* __restrict__ agg, int n4) {
    int i = blockIdx.x * 256 + threadIdx.x;
    if (i >= n4) return;
    float4 v = ((const float4*)h)[i];
    if (scale) {
        int c = (i & 31) * 4;  // 32 float4 per 128-wide row
        float4 sc = *(const float4*)(scale + c);
        float4 sh = *(const float4*)(shift + c);
        v.x = fmaxf(fmaf(v.x, sc.x, sh.x), 0.f);
        v.y = fmaxf(fmaf(v.y, sc.y, sh.y), 0.f);
        v.z = fmaxf(fmaf(v.z, sc.z, sh.z), 0.f);
        v.w = fmaxf(fmaf(v.w, sc.w, sh.w), 0.f);
    }
    ((float4*)agg)[i] = v;
}

// ---------------------------------------------------------------------------
// Scatter-add: agg[dst[e]] += BNrelu(h[src[e]]).  8 edges per 256-thread
// block; each thread handles 4 channels (float4 gather + 4 float atomics).
__global__ void k_scatter(const float* __restrict__ h,
                          const int* __restrict__ src,
                          const int* __restrict__ dst,
                          const float* __restrict__ scale,
                          const float* __restrict__ shift,
                          float* __restrict__ agg, int nE) {
    int t = threadIdx.x;
    int e = blockIdx.x * 8 + (t >> 5);
    if (e >= nE) return;
    int c = (t & 31) * 4;
    int s = src[e];
    int d = dst[e];
    float4 v = *(const float4*)(h + (size_t)s * DIM + c);
    if (scale) {
        float4 sc = *(const float4*)(scale + c);
        float4 sh = *(const float4*)(shift + c);
        v.x = fmaxf(fmaf(v.x, sc.x, sh.x), 0.f);
        v.y = fmaxf(fmaf(v.y, sc.y, sh.y), 0.f);
        v.z = fmaxf(fmaf(v.z, sc.z, sh.z), 0.f);
        v.w = fmaxf(fmaf(v.w, sc.w, sh.w), 0.f);
    }
    float* o = agg + (size_t)d * DIM + c;
    atomicAdd(o + 0, v.x);
    atomicAdd(o + 1, v.y);
    atomicAdd(o + 2, v.z);
    atomicAdd(o + 3, v.w);
}

// ---------------------------------------------------------------------------
// C[M x 128] = BNrelu(A)[M x 128] @ W[128 x 128] + bias, with optional
// column sum/sumsq stats (for the following BatchNorm) via LDS reduction +
// one atomic per column per block.
// Block: 256 threads (tr = t>>4, tc = t&15); tile 128 rows; each thread
// computes 8 rows x 8 cols (cols tc*4..+3 and 64+tc*4..+3).
// LDS: As[32][132] transposed A-chunk (pad 4 keeps 16B align, ~free banks),
//      Ws[32][128] W-chunk.
__global__ void k_gemm(const float* __restrict__ A,
                       const float* __restrict__ W,
                       const float* __restrict__ bias,
                       const float* __restrict__ scale,
                       const float* __restrict__ shift,
                       float* __restrict__ C,
                       float* __restrict__ statSum,
                       float* __restrict__ statSq, int M) {
    __shared__ float lds[8320];  // As: 32*132=4224 @0, Ws: 4096 @4224
    float* As = lds;
    float* Ws = lds + 4224;

    const int t = threadIdx.x;
    const int tr = t >> 4;
    const int tc = t & 15;
    const int rowBase = blockIdx.x * 128;

    float acc[8][8];
#pragma unroll
    for (int i = 0; i < 8; ++i)
#pragma unroll
        for (int j = 0; j < 8; ++j) acc[i][j] = 0.f;

    for (int kc = 0; kc < 4; ++kc) {
        // --- stage A chunk (128 rows x 32 k), transposed into As[k][row]
#pragma unroll
        for (int i = 0; i < 4; ++i) {
            int idx = t + i * 256;      // 0..1023
            int row = idx >> 3;
            int kg = idx & 7;           // group of 4 k's
            int grow = rowBase + row;
            int gr = grow < M ? grow : M - 1;
            float4 v = *(const float4*)(A + (size_t)gr * DIM + kc * 32 + kg * 4);
            if (scale) {
                float4 sc = *(const float4*)(scale + kc * 32 + kg * 4);
                float4 sh = *(const float4*)(shift + kc * 32 + kg * 4);
                v.x = fmaxf(fmaf(v.x, sc.x, sh.x), 0.f);
                v.y = fmaxf(fmaf(v.y, sc.y, sh.y), 0.f);
                v.z = fmaxf(fmaf(v.z, sc.z, sh.z), 0.f);
                v.w = fmaxf(fmaf(v.w, sc.w, sh.w), 0.f);
            }
            int k = kg * 4;
            As[(k + 0) * 132 + row] = v.x;
            As[(k + 1) * 132 + row] = v.y;
            As[(k + 2) * 132 + row] = v.z;
            As[(k + 3) * 132 + row] = v.w;
        }
        // --- stage W chunk (32 k x 128 cols), natural layout
#pragma unroll
        for (int i = 0; i < 4; ++i) {
            int idx = t + i * 256;
            int k = idx >> 5;
            int cg = idx & 31;
            *(float4*)(Ws + k * 128 + cg * 4) =
                *(const float4*)(W + (size_t)(kc * 32 + k) * DIM + cg * 4);
        }
        __syncthreads();

#pragma unroll
        for (int k = 0; k < 32; ++k) {
            float a[8], b[8];
            *(float4*)&a[0] = *(const float4*)(As + k * 132 + tr * 8);
            *(float4*)&a[4] = *(const float4*)(As + k * 132 + tr * 8 + 4);
            *(float4*)&b[0] = *(const float4*)(Ws + k * 128 + tc * 4);
            *(float4*)&b[4] = *(const float4*)(Ws + k * 128 + 64 + tc * 4);
#pragma unroll
            for (int i = 0; i < 8; ++i)
#pragma unroll
                for (int j = 0; j < 8; ++j)
                    acc[i][j] = fmaf(a[i], b[j], acc[i][j]);
        }
        __syncthreads();
    }

    // --- epilogue: bias, store, per-column stats
    float bc[8];
    *(float4*)&bc[0] = *(const float4*)(bias + tc * 4);
    *(float4*)&bc[4] = *(const float4*)(bias + 64 + tc * 4);

    float csum[8], csq[8];
#pragma unroll
    for (int j = 0; j < 8; ++j) { csum[j] = 0.f; csq[j] = 0.f; }

#pragma unroll
    for (int i = 0; i < 8; ++i) {
        int row = rowBase + tr * 8 + i;
        if (row < M) {
            float o[8];
#pragma unroll
            for (int j = 0; j < 8; ++j) {
                o[j] = acc[i][j] + bc[j];
                csum[j] += o[j];
                csq[j] += o[j] * o[j];
            }
            *(float4*)(C + (size_t)row * DIM + tc * 4) = *(float4*)&o[0];
            *(float4*)(C + (size_t)row * DIM + 64 + tc * 4) = *(float4*)&o[4];
        }
    }

    if (statSum) {
        // block reduction in LDS (reuse; safe: barrier above ended all reads)
#pragma unroll
        for (int j = 0; j < 4; ++j) {
            lds[tr * 128 + tc * 4 + j] = csum[j];
            lds[tr * 128 + 64 + tc * 4 + j] = csum[4 + j];
            lds[2048 + tr * 128 + tc * 4 + j] = csq[j];
            lds[2048 + tr * 128 + 64 + tc * 4 + j] = csq[4 + j];
        }
        __syncthreads();
        if (t < 128) {
            float s = 0.f, q = 0.f;
#pragma unroll
            for (int g = 0; g < 16; ++g) {
                s += lds[g * 128 + t];
                q += lds[2048 + g * 128 + t];
            }
            atomicAdd(statSum + t, s);
            atomicAdd(statSq + t, q);
        }
    }
}

// ---------------------------------------------------------------------------
// scale/shift from accumulated column stats: biased var (matches jnp.var).
__global__ void k_bnfin(const float* __restrict__ sum,
                        const float* __restrict__ sq,
                        const float* __restrict__ g,
                        const float* __restrict__ be,
                        float* __restrict__ scale,
                        float* __restrict__ shift, float invN) {
    int c = threadIdx.x;
    float mu = sum[c] * invN;
    float var = sq[c] * invN - mu * mu;
    float inv = rsqrtf(var + 1e-5f);
    float s = g[c] * inv;
    scale[c] = s;
    shift[c] = be[c] - mu * s;
}

// ---------------------------------------------------------------------------
// Row-wise L2 normalize: one wave per row (lane holds float2).
__global__ void k_l2norm(const float* __restrict__ h, float* __restrict__ out,
                         int M) {
    int w = threadIdx.x >> 6;
    int lane = threadIdx.x & 63;
    int row = blockIdx.x * 4 + w;
    if (row >= M) return;
    float2 v = *(const float2*)(h + (size_t)row * DIM + lane * 2);
    float ss = v.x * v.x + v.y * v.y;
#pragma unroll
    for (int o = 32; o; o >>= 1) ss += __shfl_xor(ss, o);
    float inv = 1.f / fmaxf(sqrtf(ss), 1e-12f);
    float2 r;
    r.x = v.x * inv;
    r.y = v.y * inv;
    *(float2*)(out + (size_t)row * DIM + lane * 2) = r;
}

// ---------------------------------------------------------------------------
extern "C" void kernel_launch(void* const* d_in, const int* in_sizes, int n_in,
                              void* d_out, int out_size, void* d_ws,
                              size_t ws_size, hipStream_t stream) {
    const float* x = (const float*)d_in[0];
    const int* ei = (const int*)d_in[1];
    const float* W1 = (const float*)d_in[2];
    const float* b1 = (const float*)d_in[3];
    const float* g1 = (const float*)d_in[4];
    const float* be1 = (const float*)d_in[5];
    const float* W2 = (const float*)d_in[6];
    const float* b2 = (const float*)d_in[7];
    const float* g_out = (const float*)d_in[8];
    const float* b_out = (const float*)d_in[9];
    float* out = (float*)d_out;

    const int M = M_NODES;
    const int E = N_EDGES_TOT;
    const size_t NM = (size_t)M * DIM;

    float* P0 = (float*)d_ws;
    float* P1 = P0 + NM;
    float* st = P1 + NM;  // sum[128], sq[128], sc1[128], sh1[128], sc2[128], sh2[128]
    float* sum = st;
    float* sq = st + 128;
    float* sc1 = st + 256;
    float* sh1 = st + 384;
    float* sc2 = st + 512;
    float* sh2 = st + 640;

    const int* src = ei;
    const int* dst = ei + E;

    const int n4 = (int)(NM / 4);
    const int initGrid = (n4 + 255) / 256;
    const int scatGrid = E / 8;
    const int gemmGrid = (M + 127) / 128;
    const float invN = 1.f / (float)M;

    // ---------------- layer 0 ----------------
    k_init<<<initGrid, 256, 0, stream>>>(x, nullptr, nullptr, P0, n4);
    k_scatter<<<scatGrid, 256, 0, stream>>>(x, src, dst, nullptr, nullptr, P0, E);
    k_zero<<<1, 256, 0, stream>>>(sum, 256);
    k_gemm<<<gemmGrid, 256, 0, stream>>>(P0, W1, b1, nullptr, nullptr, P1, sum, sq, M);
    k_bnfin<<<1, 128, 0, stream>>>(sum, sq, g1, be1, sc1, sh1, invN);
    k_zero<<<1, 256, 0, stream>>>(sum, 256);
    k_gemm<<<gemmGrid, 256, 0, stream>>>(P1, W2, b2, sc1, sh1, out, sum, sq, M);
    k_bnfin<<<1, 128, 0, stream>>>(sum, sq, g_out, b_out, sc2, sh2, invN);

    // ---------------- layer 1 ----------------
    k_init<<<initGrid, 256, 0, stream>>>(out, sc2, sh2, P0, n4);
    k_scatter<<<scatGrid, 256, 0, stream>>>(out, src, dst, sc2, sh2, P0, E);
    k_zero<<<1, 256, 0, stream>>>(sum, 256);
    k_gemm<<<gemmGrid, 256, 0, stream>>>(P0, W1 + 16384, b1 + 128, nullptr, nullptr, P1, sum, sq, M);
    k_bnfin<<<1, 128, 0, stream>>>(sum, sq, g1 + 128, be1 + 128, sc1, sh1, invN);
    k_zero<<<1, 256, 0, stream>>>(sum, 256);
    k_gemm<<<gemmGrid, 256, 0, stream>>>(P1, W2 + 16384, b2 + 128, sc1, sh1, out, sum, sq, M);
    k_bnfin<<<1, 128, 0, stream>>>(sum, sq, g_out + 128, b_out + 128, sc2, sh2, invN);

    // ---------------- layer 2 ----------------
    k_init<<<initGrid, 256, 0, stream>>>(out, sc2, sh2, P0, n4);
    k_scatter<<<scatGrid, 256, 0, stream>>>(out, src, dst, sc2, sh2, P0, E);
    k_zero<<<1, 256, 0, stream>>>(sum, 256);
    k_gemm<<<gemmGrid, 256, 0, stream>>>(P0, W1 + 32768, b1 + 256, nullptr, nullptr, P1, sum, sq, M);
    k_bnfin<<<1, 128, 0, stream>>>(sum, sq, g1 + 256, be1 + 256, sc1, sh1, invN);
    k_gemm<<<gemmGrid, 256, 0, stream>>>(P1, W2 + 32768, b2 + 256, sc1, sh1, P0, nullptr, nullptr, M);

    // ---------------- final L2 normalize ----------------
    k_l2norm<<<(M + 3) / 4, 256, 0, stream>>>(P0, out, M);
}

// Round 2
// 1045.242 us; speedup vs baseline: 8.1893x; 8.1893x over previous
//
#include <hip/hip_runtime.h>

#define M_NODES 100000
#define DIM 128
#define N_EDGES_TOT 1600000

// ---------------------------------------------------------------------------
__global__ void k_zerof(float* p, int n) {
    int i = blockIdx.x * 256 + threadIdx.x;
    if (i < n) p[i] = 0.f;
}
__global__ void k_zeroi(int* p, int n) {
    int i = blockIdx.x * 256 + threadIdx.x;
    if (i < n) p[i] = 0;
}

// ---------------------------------------------------------------------------
// CSR build: histogram of dst -> exclusive scan -> bucket fill of src ids.
__global__ void k_hist(const int* __restrict__ dst, int* __restrict__ cnt,
                       int nE) {
    int e = blockIdx.x * 256 + threadIdx.x;
    if (e < nE) atomicAdd(&cnt[dst[e]], 1);
}

__global__ void k_scanA(const int* __restrict__ cnt, int* __restrict__ excl,
                        int* __restrict__ bsum, int n) {
    __shared__ int s[256];
    int t = threadIdx.x, i = blockIdx.x * 256 + t;
    int v = (i < n) ? cnt[i] : 0;
    s[t] = v;
    __syncthreads();
#pragma unroll
    for (int o = 1; o < 256; o <<= 1) {
        int a = (t >= o) ? s[t - o] : 0;
        __syncthreads();
        s[t] += a;
        __syncthreads();
    }
    if (i < n) excl[i] = s[t] - v;
    if (t == 255) bsum[blockIdx.x] = s[255];
}

__global__ void k_scanB(int* bsum, int nB) {
    __shared__ int s[512];
    int t = threadIdx.x;
    int v = (t < nB) ? bsum[t] : 0;
    s[t] = v;
    __syncthreads();
#pragma unroll
    for (int o = 1; o < 512; o <<= 1) {
        int a = (t >= o) ? s[t - o] : 0;
        __syncthreads();
        s[t] += a;
        __syncthreads();
    }
    if (t < nB) bsum[t] = s[t] - v;
}

__global__ void k_scanC(int* __restrict__ rowptr, int* __restrict__ cursor,
                        const int* __restrict__ bsum, int n, int total) {
    int t = threadIdx.x, i = blockIdx.x * 256 + t;
    if (i < n) {
        int r = rowptr[i] + bsum[blockIdx.x];
        rowptr[i] = r;
        cursor[i] = r;
    } else if (i == n) {
        rowptr[n] = total;
    }
}

__global__ void k_fill(const int* __restrict__ src, const int* __restrict__ dst,
                       int* __restrict__ cursor, int* __restrict__ srcs,
                       int nE) {
    int e = blockIdx.x * 256 + threadIdx.x;
    if (e >= nE) return;
    int p = atomicAdd(&cursor[dst[e]], 1);
    srcs[p] = src[e];
}

// ---------------------------------------------------------------------------
// Aggregation as a gather: agg[i] = BNrelu(h[i]) + sum_{e:dst=i} BNrelu(h[src]).
// 32 lanes per node (lane owns 4 channels); neighbor rows read as coalesced
// 512B bursts from L3-resident h. No f32 atomics anywhere.
__global__ void k_gather(const float* __restrict__ h,
                         const int* __restrict__ rowptr,
                         const int* __restrict__ srcs,
                         const float* __restrict__ scale,
                         const float* __restrict__ shift,
                         float* __restrict__ agg, int M) {
    int t = threadIdx.x;
    int node = blockIdx.x * 8 + (t >> 5);
    if (node >= M) return;
    int c = (t & 31) * 4;
    const bool bn = (scale != nullptr);
    float4 sc = make_float4(1.f, 1.f, 1.f, 1.f);
    float4 sh = make_float4(0.f, 0.f, 0.f, 0.f);
    if (bn) {
        sc = *(const float4*)(scale + c);
        sh = *(const float4*)(shift + c);
    }
    int beg = rowptr[node];
    int end = rowptr[node + 1];

    float4 acc = *(const float4*)(h + (size_t)node * DIM + c);
    if (bn) {
        acc.x = fmaxf(fmaf(acc.x, sc.x, sh.x), 0.f);
        acc.y = fmaxf(fmaf(acc.y, sc.y, sh.y), 0.f);
        acc.z = fmaxf(fmaf(acc.z, sc.z, sh.z), 0.f);
        acc.w = fmaxf(fmaf(acc.w, sc.w, sh.w), 0.f);
    }
    for (int j = beg; j < end; ++j) {
        int s = srcs[j];
        float4 v = *(const float4*)(h + (size_t)s * DIM + c);
        if (bn) {
            v.x = fmaxf(fmaf(v.x, sc.x, sh.x), 0.f);
            v.y = fmaxf(fmaf(v.y, sc.y, sh.y), 0.f);
            v.z = fmaxf(fmaf(v.z, sc.z, sh.z), 0.f);
            v.w = fmaxf(fmaf(v.w, sc.w, sh.w), 0.f);
        }
        acc.x += v.x;
        acc.y += v.y;
        acc.z += v.z;
        acc.w += v.w;
    }
    *(float4*)(agg + (size_t)node * DIM + c) = acc;
}

// ---------------------------------------------------------------------------
// C[M x 128] = BNrelu(A)[M x 128] @ W[128 x 128] + bias, optional column
// sum/sumsq stats via LDS reduction + one atomic per column per block.
__global__ void k_gemm(const float* __restrict__ A,
                       const float* __restrict__ W,
                       const float* __restrict__ bias,
                       const float* __restrict__ scale,
                       const float* __restrict__ shift,
                       float* __restrict__ C,
                       float* __restrict__ statSum,
                       float* __restrict__ statSq, int M) {
    __shared__ float lds[8320];  // As: 32*132=4224 @0, Ws: 4096 @4224
    float* As = lds;
    float* Ws = lds + 4224;

    const int t = threadIdx.x;
    const int tr = t >> 4;
    const int tc = t & 15;
    const int rowBase = blockIdx.x * 128;

    float acc[8][8];
#pragma unroll
    for (int i = 0; i < 8; ++i)
#pragma unroll
        for (int j = 0; j < 8; ++j) acc[i][j] = 0.f;

    for (int kc = 0; kc < 4; ++kc) {
#pragma unroll
        for (int i = 0; i < 4; ++i) {
            int idx = t + i * 256;  // 0..1023
            int row = idx >> 3;
            int kg = idx & 7;
            int grow = rowBase + row;
            int gr = grow < M ? grow : M - 1;
            float4 v = *(const float4*)(A + (size_t)gr * DIM + kc * 32 + kg * 4);
            if (scale) {
                float4 sc = *(const float4*)(scale + kc * 32 + kg * 4);
                float4 sh = *(const float4*)(shift + kc * 32 + kg * 4);
                v.x = fmaxf(fmaf(v.x, sc.x, sh.x), 0.f);
                v.y = fmaxf(fmaf(v.y, sc.y, sh.y), 0.f);
                v.z = fmaxf(fmaf(v.z, sc.z, sh.z), 0.f);
                v.w = fmaxf(fmaf(v.w, sc.w, sh.w), 0.f);
            }
            int k = kg * 4;
            As[(k + 0) * 132 + row] = v.x;
            As[(k + 1) * 132 + row] = v.y;
            As[(k + 2) * 132 + row] = v.z;
            As[(k + 3) * 132 + row] = v.w;
        }
#pragma unroll
        for (int i = 0; i < 4; ++i) {
            int idx = t + i * 256;
            int k = idx >> 5;
            int cg = idx & 31;
            *(float4*)(Ws + k * 128 + cg * 4) =
                *(const float4*)(W + (size_t)(kc * 32 + k) * DIM + cg * 4);
        }
        __syncthreads();

#pragma unroll
        for (int k = 0; k < 32; ++k) {
            float a[8], b[8];
            *(float4*)&a[0] = *(const float4*)(As + k * 132 + tr * 8);
            *(float4*)&a[4] = *(const float4*)(As + k * 132 + tr * 8 + 4);
            *(float4*)&b[0] = *(const float4*)(Ws + k * 128 + tc * 4);
            *(float4*)&b[4] = *(const float4*)(Ws + k * 128 + 64 + tc * 4);
#pragma unroll
            for (int i = 0; i < 8; ++i)
#pragma unroll
                for (int j = 0; j < 8; ++j)
                    acc[i][j] = fmaf(a[i], b[j], acc[i][j]);
        }
        __syncthreads();
    }

    float bc[8];
    *(float4*)&bc[0] = *(const float4*)(bias + tc * 4);
    *(float4*)&bc[4] = *(const float4*)(bias + 64 + tc * 4);

    float csum[8], csq[8];
#pragma unroll
    for (int j = 0; j < 8; ++j) { csum[j] = 0.f; csq[j] = 0.f; }

#pragma unroll
    for (int i = 0; i < 8; ++i) {
        int row = rowBase + tr * 8 + i;
        if (row < M) {
            float o[8];
#pragma unroll
            for (int j = 0; j < 8; ++j) {
                o[j] = acc[i][j] + bc[j];
                csum[j] += o[j];
                csq[j] += o[j] * o[j];
            }
            *(float4*)(C + (size_t)row * DIM + tc * 4) = *(float4*)&o[0];
            *(float4*)(C + (size_t)row * DIM + 64 + tc * 4) = *(float4*)&o[4];
        }
    }

    if (statSum) {
#pragma unroll
        for (int j = 0; j < 4; ++j) {
            lds[tr * 128 + tc * 4 + j] = csum[j];
            lds[tr * 128 + 64 + tc * 4 + j] = csum[4 + j];
            lds[2048 + tr * 128 + tc * 4 + j] = csq[j];
            lds[2048 + tr * 128 + 64 + tc * 4 + j] = csq[4 + j];
        }
        __syncthreads();
        if (t < 128) {
            float s = 0.f, q = 0.f;
#pragma unroll
            for (int g = 0; g < 16; ++g) {
                s += lds[g * 128 + t];
                q += lds[2048 + g * 128 + t];
            }
            atomicAdd(statSum + t, s);
            atomicAdd(statSq + t, q);
        }
    }
}

// ---------------------------------------------------------------------------
__global__ void k_bnfin(const float* __restrict__ sum,
                        const float* __restrict__ sq,
                        const float* __restrict__ g,
                        const float* __restrict__ be,
                        float* __restrict__ scale,
                        float* __restrict__ shift, float invN) {
    int c = threadIdx.x;
    float mu = sum[c] * invN;
    float var = sq[c] * invN - mu * mu;
    float inv = rsqrtf(var + 1e-5f);
    float s = g[c] * inv;
    scale[c] = s;
    shift[c] = be[c] - mu * s;
}

// ---------------------------------------------------------------------------
__global__ void k_l2norm(const float* __restrict__ h, float* __restrict__ out,
                         int M) {
    int w = threadIdx.x >> 6;
    int lane = threadIdx.x & 63;
    int row = blockIdx.x * 4 + w;
    if (row >= M) return;
    float2 v = *(const float2*)(h + (size_t)row * DIM + lane * 2);
    float ss = v.x * v.x + v.y * v.y;
#pragma unroll
    for (int o = 32; o; o >>= 1) ss += __shfl_xor(ss, o);
    float inv = 1.f / fmaxf(sqrtf(ss), 1e-12f);
    float2 r;
    r.x = v.x * inv;
    r.y = v.y * inv;
    *(float2*)(out + (size_t)row * DIM + lane * 2) = r;
}

// ---------------------------------------------------------------------------
extern "C" void kernel_launch(void* const* d_in, const int* in_sizes, int n_in,
                              void* d_out, int out_size, void* d_ws,
                              size_t ws_size, hipStream_t stream) {
    const float* x = (const float*)d_in[0];
    const int* ei = (const int*)d_in[1];
    const float* W1 = (const float*)d_in[2];
    const float* b1 = (const float*)d_in[3];
    const float* g1 = (const float*)d_in[4];
    const float* be1 = (const float*)d_in[5];
    const float* W2 = (const float*)d_in[6];
    const float* b2 = (const float*)d_in[7];
    const float* g_out = (const float*)d_in[8];
    const float* b_out = (const float*)d_in[9];
    float* out = (float*)d_out;

    const int M = M_NODES;
    const int E = N_EDGES_TOT;
    const size_t NM = (size_t)M * DIM;

    float* P0 = (float*)d_ws;
    float* P1 = P0 + NM;
    float* st = P1 + NM;  // sum,sq,sc1,sh1,sc2,sh2 (6*128)
    float* sum = st;
    float* sq = st + 128;
    float* sc1 = st + 256;
    float* sh1 = st + 384;
    float* sc2 = st + 512;
    float* sh2 = st + 640;
    int* rowptr = (int*)(st + 768);            // M+1
    int* cursor = rowptr + (M + 1);            // M
    int* bsum = cursor + M;                    // 512
    int* srcs = bsum + 512;                    // E

    const int* src = ei;
    const int* dst = ei + E;

    const int gemmGrid = (M + 127) / 128;
    const int gathGrid = (M + 7) / 8;
    const int nB = (M + 255) / 256;            // 391 scan blocks
    const float invN = 1.f / (float)M;

    // ---------------- CSR build (per call; reused by all 3 layers) --------
    k_zeroi<<<(M + 255) / 256, 256, 0, stream>>>(cursor, M);
    k_hist<<<(E + 255) / 256, 256, 0, stream>>>(dst, cursor, E);
    k_scanA<<<nB, 256, 0, stream>>>(cursor, rowptr, bsum, M);
    k_scanB<<<1, 512, 0, stream>>>(bsum, nB);
    k_scanC<<<nB, 256, 0, stream>>>(rowptr, cursor, bsum, M, E);
    k_fill<<<(E + 255) / 256, 256, 0, stream>>>(src, dst, cursor, srcs, E);

    // ---------------- layer 0 ----------------
    k_gather<<<gathGrid, 256, 0, stream>>>(x, rowptr, srcs, nullptr, nullptr, P0, M);
    k_zerof<<<1, 256, 0, stream>>>(sum, 256);
    k_gemm<<<gemmGrid, 256, 0, stream>>>(P0, W1, b1, nullptr, nullptr, P1, sum, sq, M);
    k_bnfin<<<1, 128, 0, stream>>>(sum, sq, g1, be1, sc1, sh1, invN);
    k_zerof<<<1, 256, 0, stream>>>(sum, 256);
    k_gemm<<<gemmGrid, 256, 0, stream>>>(P1, W2, b2, sc1, sh1, out, sum, sq, M);
    k_bnfin<<<1, 128, 0, stream>>>(sum, sq, g_out, b_out, sc2, sh2, invN);

    // ---------------- layer 1 ----------------
    k_gather<<<gathGrid, 256, 0, stream>>>(out, rowptr, srcs, sc2, sh2, P0, M);
    k_zerof<<<1, 256, 0, stream>>>(sum, 256);
    k_gemm<<<gemmGrid, 256, 0, stream>>>(P0, W1 + 16384, b1 + 128, nullptr, nullptr, P1, sum, sq, M);
    k_bnfin<<<1, 128, 0, stream>>>(sum, sq, g1 + 128, be1 + 128, sc1, sh1, invN);
    k_zerof<<<1, 256, 0, stream>>>(sum, 256);
    k_gemm<<<gemmGrid, 256, 0, stream>>>(P1, W2 + 16384, b2 + 128, sc1, sh1, out, sum, sq, M);
    k_bnfin<<<1, 128, 0, stream>>>(sum, sq, g_out + 128, b_out + 128, sc2, sh2, invN);

    // ---------------- layer 2 ----------------
    k_gather<<<gathGrid, 256, 0, stream>>>(out, rowptr, srcs, sc2, sh2, P0, M);
    k_zerof<<<1, 256, 0, stream>>>(sum, 256);
    k_gemm<<<gemmGrid, 256, 0, stream>>>(P0, W1 + 32768, b1 + 256, nullptr, nullptr, P1, sum, sq, M);
    k_bnfin<<<1, 128, 0, stream>>>(sum, sq, g1 + 256, be1 + 256, sc1, sh1, invN);
    k_gemm<<<gemmGrid, 256, 0, stream>>>(P1, W2 + 32768, b2 + 256, sc1, sh1, P0, nullptr, nullptr, M);

    // ---------------- final L2 normalize ----------------
    k_l2norm<<<(M + 3) / 4, 256, 0, stream>>>(P0, out, M);
}

// Round 4
// 910.457 us; speedup vs baseline: 9.4017x; 1.1480x over previous
//
#include <hip/hip_runtime.h>

#define M_NODES 100000
#define DIM 128
#define N_EDGES_TOT 1600000

typedef unsigned int uint;
typedef unsigned short ushort;
typedef __attribute__((ext_vector_type(8))) short bf16x8;
typedef __attribute__((ext_vector_type(4))) float f32x4;

__device__ __forceinline__ float bflo(uint u) { return __uint_as_float(u << 16); }
__device__ __forceinline__ float bfhi(uint u) { return __uint_as_float(u & 0xffff0000u); }
__device__ __forceinline__ float bf2f(ushort h) { return __uint_as_float(((uint)h) << 16); }
__device__ __forceinline__ ushort f2bf(float f) {
    uint u = __float_as_uint(f);
    return (ushort)((u + 0x7fffu + ((u >> 16) & 1u)) >> 16);
}
// LDS byte-offset XOR swizzle: breaks 16-way bank conflict on 256B-row tiles.
__device__ __forceinline__ int SWZ(int row, int byte) {
    return byte ^ ((row & 7) << 4);
}

// ---------------------------------------------------------------------------
__global__ void k_zerof(float* p, int n) {
    int i = blockIdx.x * 256 + threadIdx.x;
    if (i < n) p[i] = 0.f;
}
__global__ void k_zeroi(int* p, int n) {
    int i = blockIdx.x * 256 + threadIdx.x;
    if (i < n) p[i] = 0;
}

// ---------------------------------------------------------------------------
// x f32 -> bf16
__global__ void k_cvt(const float* __restrict__ x, ushort* __restrict__ xb,
                      int n4) {
    int i = blockIdx.x * 256 + threadIdx.x;
    if (i >= n4) return;
    float4 v = ((const float4*)x)[i];
    uint2 r;
    r.x = (uint)f2bf(v.x) | ((uint)f2bf(v.y) << 16);
    r.y = (uint)f2bf(v.z) | ((uint)f2bf(v.w) << 16);
    ((uint2*)xb)[i] = r;
}

// W (K x N f32) -> transposed split planes Wh/Wl (N x K bf16), 6 matrices.
__global__ void k_wprep(const float* __restrict__ W1,
                        const float* __restrict__ W2, ushort* __restrict__ Wh,
                        ushort* __restrict__ Wl) {
    int i = blockIdx.x * 256 + threadIdx.x;
    if (i >= 6 * 16384) return;
    int l = i >> 14;
    int r = i & 16383;
    int n = r >> 7, k = r & 127;
    const float* W = (l < 3) ? (W1 + l * 16384) : (W2 + (l - 3) * 16384);
    float w = W[k * 128 + n];
    ushort h = f2bf(w);
    Wh[i] = h;
    Wl[i] = f2bf(w - bf2f(h));
}

// ---------------------------------------------------------------------------
// CSR build
__global__ void k_hist(const int* __restrict__ dst, int* __restrict__ cnt,
                       int nE) {
    int e = blockIdx.x * 256 + threadIdx.x;
    if (e < nE) atomicAdd(&cnt[dst[e]], 1);
}

__global__ void k_scanA(const int* __restrict__ cnt, int* __restrict__ excl,
                        int* __restrict__ bsum, int n) {
    __shared__ int s[256];
    int t = threadIdx.x, i = blockIdx.x * 256 + t;
    int v = (i < n) ? cnt[i] : 0;
    s[t] = v;
    __syncthreads();
#pragma unroll
    for (int o = 1; o < 256; o <<= 1) {
        int a = (t >= o) ? s[t - o] : 0;
        __syncthreads();
        s[t] += a;
        __syncthreads();
    }
    if (i < n) excl[i] = s[t] - v;
    if (t == 255) bsum[blockIdx.x] = s[255];
}

__global__ void k_scanB(int* bsum, int nB) {
    __shared__ int s[512];
    int t = threadIdx.x;
    int v = (t < nB) ? bsum[t] : 0;
    s[t] = v;
    __syncthreads();
#pragma unroll
    for (int o = 1; o < 512; o <<= 1) {
        int a = (t >= o) ? s[t - o] : 0;
        __syncthreads();
        s[t] += a;
        __syncthreads();
    }
    if (t < nB) bsum[t] = s[t] - v;
}

__global__ void k_scanC(int* __restrict__ rowptr, int* __restrict__ cursor,
                        const int* __restrict__ bsum, int n, int total) {
    int t = threadIdx.x, i = blockIdx.x * 256 + t;
    if (i < n) {
        int r = rowptr[i] + bsum[blockIdx.x];
        rowptr[i] = r;
        cursor[i] = r;
    } else if (i == n) {
        rowptr[n] = total;
    }
}

__global__ void k_fill(const int* __restrict__ src, const int* __restrict__ dst,
                       int* __restrict__ cursor, int* __restrict__ srcs,
                       int nE) {
    int e = blockIdx.x * 256 + threadIdx.x;
    if (e >= nE) return;
    int p = atomicAdd(&cursor[dst[e]], 1);
    srcs[p] = src[e];
}

// ---------------------------------------------------------------------------
// Gather aggregation: bf16 in, f32 accumulate, **f32 out**.
// agg[i] = BNrelu(h[i]) + sum_{e: dst=i} BNrelu(h[src]).
__global__ void k_gather(const ushort* __restrict__ h,
                         const int* __restrict__ rowptr,
                         const int* __restrict__ srcs,
                         const float* __restrict__ scale,
                         const float* __restrict__ shift,
                         float* __restrict__ agg, int M) {
    int t = threadIdx.x;
    int node = blockIdx.x * 8 + (t >> 5);
    if (node >= M) return;
    int c = (t & 31) * 4;
    const bool bn = (scale != nullptr);
    float4 sc = make_float4(1.f, 1.f, 1.f, 1.f);
    float4 sh = make_float4(0.f, 0.f, 0.f, 0.f);
    if (bn) {
        sc = *(const float4*)(scale + c);
        sh = *(const float4*)(shift + c);
    }
    int beg = rowptr[node];
    int end = rowptr[node + 1];

    uint2 v = *(const uint2*)(h + (size_t)node * DIM + c);
    float a0 = bflo(v.x), a1 = bfhi(v.x), a2 = bflo(v.y), a3 = bfhi(v.y);
    if (bn) {
        a0 = fmaxf(fmaf(a0, sc.x, sh.x), 0.f);
        a1 = fmaxf(fmaf(a1, sc.y, sh.y), 0.f);
        a2 = fmaxf(fmaf(a2, sc.z, sh.z), 0.f);
        a3 = fmaxf(fmaf(a3, sc.w, sh.w), 0.f);
    }
    for (int j = beg; j < end; ++j) {
        int s = srcs[j];
        uint2 g = *(const uint2*)(h + (size_t)s * DIM + c);
        float f0 = bflo(g.x), f1 = bfhi(g.x), f2 = bflo(g.y), f3 = bfhi(g.y);
        if (bn) {
            f0 = fmaxf(fmaf(f0, sc.x, sh.x), 0.f);
            f1 = fmaxf(fmaf(f1, sc.y, sh.y), 0.f);
            f2 = fmaxf(fmaf(f2, sc.z, sh.z), 0.f);
            f3 = fmaxf(fmaf(f3, sc.w, sh.w), 0.f);
        }
        a0 += f0;
        a1 += f1;
        a2 += f2;
        a3 += f3;
    }
    float4 r = make_float4(a0, a1, a2, a3);
    *(float4*)(agg + (size_t)node * DIM + c) = r;
}

// ---------------------------------------------------------------------------
// Split-bf16 MFMA GEMM (near-f32): C = BNrelu(A) @ W + bias.
// A f32 row-major; staged to LDS as Ah+Al bf16 planes (BNrelu in f32 first).
// W pre-split to Wh/Wl (N x K bf16); fragments read straight from global
// (L2-resident, 128KB/block). 3-term product: AhWh + AlWh + AhWl.
// Modes: Cf!=null -> f32 store; else Cb bf16 store; stats if statSum;
//        outF!=null -> fused row L2-normalize to f32.
__global__ void __launch_bounds__(256, 2) k_gemm(
    const float* __restrict__ A, const ushort* __restrict__ Wh,
    const ushort* __restrict__ Wl, const float* __restrict__ bias,
    const float* __restrict__ scale, const float* __restrict__ shift,
    float* __restrict__ Cf, ushort* __restrict__ Cb,
    float* __restrict__ statSum, float* __restrict__ statSq,
    float* __restrict__ outF, int M) {
    __shared__ char smem[65536];
    char* Ah = smem;            // 128 rows x 256B (swizzled) hi plane
    char* Alo = smem + 32768;   // lo plane

    const int t = threadIdx.x;
    const int w = t >> 6;
    const int lane = t & 63;
    const int rquad = lane >> 4;
    const int rcol = lane & 15;
    const int rowBase = blockIdx.x * 128;

    // ---- stage A: f32 load, optional BNrelu, split to bf16 hi/lo ----
#pragma unroll
    for (int i = 0; i < 16; ++i) {
        int idx = t + i * 256;      // 4096 4-float chunks
        int row = idx >> 5;
        int ch = idx & 31;
        int grow = rowBase + row;
        if (grow >= M) grow = M - 1;
        float4 v = *(const float4*)(A + (size_t)grow * DIM + ch * 4);
        if (scale) {
            int c0 = ch * 4;
            v.x = fmaxf(fmaf(v.x, scale[c0 + 0], shift[c0 + 0]), 0.f);
            v.y = fmaxf(fmaf(v.y, scale[c0 + 1], shift[c0 + 1]), 0.f);
            v.z = fmaxf(fmaf(v.z, scale[c0 + 2], shift[c0 + 2]), 0.f);
            v.w = fmaxf(fmaf(v.w, scale[c0 + 3], shift[c0 + 3]), 0.f);
        }
        ushort h0 = f2bf(v.x), h1 = f2bf(v.y), h2 = f2bf(v.z), h3 = f2bf(v.w);
        ushort l0 = f2bf(v.x - bf2f(h0)), l1 = f2bf(v.y - bf2f(h1));
        ushort l2 = f2bf(v.z - bf2f(h2)), l3 = f2bf(v.w - bf2f(h3));
        uint2 hp, lp;
        hp.x = (uint)h0 | ((uint)h1 << 16);
        hp.y = (uint)h2 | ((uint)h3 << 16);
        lp.x = (uint)l0 | ((uint)l1 << 16);
        lp.y = (uint)l2 | ((uint)l3 << 16);
        *(uint2*)(Ah + SWZ(row, row * 256 + ch * 8)) = hp;
        *(uint2*)(Alo + SWZ(row, row * 256 + ch * 8)) = lp;
    }
    __syncthreads();

    // ---- MFMA main loop ----
    f32x4 acc[2][8];
#pragma unroll
    for (int i = 0; i < 2; ++i)
#pragma unroll
        for (int j = 0; j < 8; ++j) acc[i][j] = (f32x4){0.f, 0.f, 0.f, 0.f};

#pragma unroll
    for (int kc = 0; kc < 4; ++kc) {
        bf16x8 bh[8], bl[8];
#pragma unroll
        for (int j = 0; j < 8; ++j) {
            size_t off = (size_t)(j * 16 + rcol) * DIM + kc * 32 + rquad * 8;
            bh[j] = *(const bf16x8*)(Wh + off);
            bl[j] = *(const bf16x8*)(Wl + off);
        }
        int kb = (kc * 32 + rquad * 8) * 2;
        bf16x8 ah[2], al[2];
#pragma unroll
        for (int i = 0; i < 2; ++i) {
            int row = w * 32 + i * 16 + rcol;
            ah[i] = *(const bf16x8*)(Ah + SWZ(row, row * 256 + kb));
            al[i] = *(const bf16x8*)(Alo + SWZ(row, row * 256 + kb));
        }
#pragma unroll
        for (int i = 0; i < 2; ++i)
#pragma unroll
            for (int j = 0; j < 8; ++j) {
                acc[i][j] = __builtin_amdgcn_mfma_f32_16x16x32_bf16(
                    ah[i], bh[j], acc[i][j], 0, 0, 0);
                acc[i][j] = __builtin_amdgcn_mfma_f32_16x16x32_bf16(
                    al[i], bh[j], acc[i][j], 0, 0, 0);
                acc[i][j] = __builtin_amdgcn_mfma_f32_16x16x32_bf16(
                    ah[i], bl[j], acc[i][j], 0, 0, 0);
            }
    }

    // ---- epilogue ----
    float bc[8];
#pragma unroll
    for (int j = 0; j < 8; ++j) bc[j] = bias[j * 16 + rcol];

    if (outF) {  // fused L2 normalize
#pragma unroll
        for (int i = 0; i < 2; ++i) {
#pragma unroll
            for (int r = 0; r < 4; ++r) {
                int row = rowBase + w * 32 + i * 16 + rquad * 4 + r;
                float o[8];
                float ss = 0.f;
#pragma unroll
                for (int j = 0; j < 8; ++j) {
                    o[j] = acc[i][j][r] + bc[j];
                    ss += o[j] * o[j];
                }
                ss += __shfl_xor(ss, 1);
                ss += __shfl_xor(ss, 2);
                ss += __shfl_xor(ss, 4);
                ss += __shfl_xor(ss, 8);
                float inv = 1.f / fmaxf(sqrtf(ss), 1e-12f);
                if (row < M) {
#pragma unroll
                    for (int j = 0; j < 8; ++j)
                        outF[(size_t)row * DIM + j * 16 + rcol] = o[j] * inv;
                }
            }
        }
        return;
    }

    // stats mode: store (f32 or bf16) + column sum/sumsq
    float csum[8], csq[8];
#pragma unroll
    for (int j = 0; j < 8; ++j) { csum[j] = 0.f; csq[j] = 0.f; }
#pragma unroll
    for (int i = 0; i < 2; ++i) {
#pragma unroll
        for (int r = 0; r < 4; ++r) {
            int row = rowBase + w * 32 + i * 16 + rquad * 4 + r;
            if (row < M) {
#pragma unroll
                for (int j = 0; j < 8; ++j) {
                    float o = acc[i][j][r] + bc[j];
                    if (Cf) Cf[(size_t)row * DIM + j * 16 + rcol] = o;
                    else Cb[(size_t)row * DIM + j * 16 + rcol] = f2bf(o);
                    csum[j] += o;
                    csq[j] += o * o;
                }
            }
        }
    }
#pragma unroll
    for (int j = 0; j < 8; ++j) {
        csum[j] += __shfl_xor(csum[j], 16);
        csum[j] += __shfl_xor(csum[j], 32);
        csq[j] += __shfl_xor(csq[j], 16);
        csq[j] += __shfl_xor(csq[j], 32);
    }
    __syncthreads();  // all LDS reads done; reuse for cross-wave reduce
    float* red = (float*)smem;
    if (lane < 16) {
#pragma unroll
        for (int j = 0; j < 8; ++j) {
            red[w * 128 + j * 16 + rcol] = csum[j];
            red[512 + w * 128 + j * 16 + rcol] = csq[j];
        }
    }
    __syncthreads();
    if (t < 128) {
        float s = red[t] + red[128 + t] + red[256 + t] + red[384 + t];
        float q = red[512 + t] + red[640 + t] + red[768 + t] + red[896 + t];
        atomicAdd(statSum + t, s);
        atomicAdd(statSq + t, q);
    }
}

// ---------------------------------------------------------------------------
__global__ void k_bnfin(const float* __restrict__ sum,
                        const float* __restrict__ sq,
                        const float* __restrict__ g,
                        const float* __restrict__ be,
                        float* __restrict__ scale,
                        float* __restrict__ shift, float invN) {
    int c = threadIdx.x;
    float mu = sum[c] * invN;
    float var = sq[c] * invN - mu * mu;
    float inv = rsqrtf(var + 1e-5f);
    float s = g[c] * inv;
    scale[c] = s;
    shift[c] = be[c] - mu * s;
}

// ---------------------------------------------------------------------------
extern "C" void kernel_launch(void* const* d_in, const int* in_sizes, int n_in,
                              void* d_out, int out_size, void* d_ws,
                              size_t ws_size, hipStream_t stream) {
    const float* x = (const float*)d_in[0];
    const int* ei = (const int*)d_in[1];
    const float* W1 = (const float*)d_in[2];
    const float* b1 = (const float*)d_in[3];
    const float* g1 = (const float*)d_in[4];
    const float* be1 = (const float*)d_in[5];
    const float* W2 = (const float*)d_in[6];
    const float* b2 = (const float*)d_in[7];
    const float* g_out = (const float*)d_in[8];
    const float* b_out = (const float*)d_in[9];
    float* out = (float*)d_out;

    const int M = M_NODES;
    const int E = N_EDGES_TOT;
    const size_t NM = (size_t)M * DIM;

    float* AGC = (float*)d_ws;       // f32: gather out / GEMM1 in-place out
    ushort* B0 = (ushort*)(AGC + NM);  // bf16 h buffer (gather input)
    ushort* Wh = B0 + NM;              // 6*16384 bf16 hi
    ushort* Wl = Wh + 6 * 16384;       // 6*16384 bf16 lo
    float* st = (float*)(Wl + 6 * 16384);
    float* sum = st;
    float* sq = st + 128;
    float* sc1 = st + 256;
    float* sh1 = st + 384;
    float* sc2 = st + 512;
    float* sh2 = st + 640;
    int* rowptr = (int*)(st + 768);
    int* cursor = rowptr + (M + 1);
    int* bsum = cursor + M;
    int* srcs = bsum + 512;

    const int* src = ei;
    const int* dst = ei + E;

    const int gemmGrid = (M + 127) / 128;
    const int gathGrid = (M + 7) / 8;
    const int nB = (M + 255) / 256;
    const float invN = 1.f / (float)M;

    // ---------------- prep: CSR + conversions --------------------
    k_zeroi<<<(M + 255) / 256, 256, 0, stream>>>(cursor, M);
    k_hist<<<(E + 255) / 256, 256, 0, stream>>>(dst, cursor, E);
    k_scanA<<<nB, 256, 0, stream>>>(cursor, rowptr, bsum, M);
    k_scanB<<<1, 512, 0, stream>>>(bsum, nB);
    k_scanC<<<nB, 256, 0, stream>>>(rowptr, cursor, bsum, M, E);
    k_fill<<<(E + 255) / 256, 256, 0, stream>>>(src, dst, cursor, srcs, E);
    k_cvt<<<(int)((NM / 4 + 255) / 256), 256, 0, stream>>>(x, B0, (int)(NM / 4));
    k_wprep<<<(6 * 16384 + 255) / 256, 256, 0, stream>>>(W1, W2, Wh, Wl);

    // ---------------- layer 0 ----------------
    k_gather<<<gathGrid, 256, 0, stream>>>(B0, rowptr, srcs, nullptr, nullptr, AGC, M);
    k_zerof<<<1, 256, 0, stream>>>(sum, 256);
    k_gemm<<<gemmGrid, 256, 0, stream>>>(AGC, Wh, Wl, b1, nullptr, nullptr,
                                         AGC, nullptr, sum, sq, nullptr, M);
    k_bnfin<<<1, 128, 0, stream>>>(sum, sq, g1, be1, sc1, sh1, invN);
    k_zerof<<<1, 256, 0, stream>>>(sum, 256);
    k_gemm<<<gemmGrid, 256, 0, stream>>>(AGC, Wh + 3 * 16384, Wl + 3 * 16384, b2,
                                         sc1, sh1, nullptr, B0, sum, sq, nullptr, M);
    k_bnfin<<<1, 128, 0, stream>>>(sum, sq, g_out, b_out, sc2, sh2, invN);

    // ---------------- layer 1 ----------------
    k_gather<<<gathGrid, 256, 0, stream>>>(B0, rowptr, srcs, sc2, sh2, AGC, M);
    k_zerof<<<1, 256, 0, stream>>>(sum, 256);
    k_gemm<<<gemmGrid, 256, 0, stream>>>(AGC, Wh + 16384, Wl + 16384, b1 + 128,
                                         nullptr, nullptr, AGC, nullptr, sum, sq, nullptr, M);
    k_bnfin<<<1, 128, 0, stream>>>(sum, sq, g1 + 128, be1 + 128, sc1, sh1, invN);
    k_zerof<<<1, 256, 0, stream>>>(sum, 256);
    k_gemm<<<gemmGrid, 256, 0, stream>>>(AGC, Wh + 4 * 16384, Wl + 4 * 16384, b2 + 128,
                                         sc1, sh1, nullptr, B0, sum, sq, nullptr, M);
    k_bnfin<<<1, 128, 0, stream>>>(sum, sq, g_out + 128, b_out + 128, sc2, sh2, invN);

    // ---------------- layer 2 ----------------
    k_gather<<<gathGrid, 256, 0, stream>>>(B0, rowptr, srcs, sc2, sh2, AGC, M);
    k_zerof<<<1, 256, 0, stream>>>(sum, 256);
    k_gemm<<<gemmGrid, 256, 0, stream>>>(AGC, Wh + 2 * 16384, Wl + 2 * 16384, b1 + 256,
                                         nullptr, nullptr, AGC, nullptr, sum, sq, nullptr, M);
    k_bnfin<<<1, 128, 0, stream>>>(sum, sq, g1 + 256, be1 + 256, sc1, sh1, invN);
    // final GEMM: fused L2 normalize, f32 straight to d_out
    k_gemm<<<gemmGrid, 256, 0, stream>>>(AGC, Wh + 5 * 16384, Wl + 5 * 16384, b2 + 256,
                                         sc1, sh1, nullptr, nullptr, nullptr, nullptr, out, M);
}

// Round 5
// 771.196 us; speedup vs baseline: 11.0994x; 1.1806x over previous
//
#include <hip/hip_runtime.h>

#define M_NODES 100000
#define DIM 128
#define N_EDGES_TOT 1600000

typedef unsigned int uint;
typedef unsigned short ushort;
typedef __attribute__((ext_vector_type(8))) short bf16x8;
typedef __attribute__((ext_vector_type(4))) float f32x4;

__device__ __forceinline__ float bflo(uint u) { return __uint_as_float(u << 16); }
__device__ __forceinline__ float bfhi(uint u) { return __uint_as_float(u & 0xffff0000u); }
__device__ __forceinline__ float bf2f(ushort h) { return __uint_as_float(((uint)h) << 16); }
__device__ __forceinline__ ushort f2bf(float f) {
    uint u = __float_as_uint(f);
    return (ushort)((u + 0x7fffu + ((u >> 16) & 1u)) >> 16);
}
// LDS byte-offset XOR swizzle: breaks 16-way bank conflict on 256B-row tiles.
__device__ __forceinline__ int SWZ(int row, int byte) {
    return byte ^ ((row & 7) << 4);
}

// ---------------------------------------------------------------------------
__global__ void k_zerof(float* p, int n) {
    int i = blockIdx.x * 256 + threadIdx.x;
    if (i < n) p[i] = 0.f;
}
__global__ void k_zeroi(int* p, int n) {
    int i = blockIdx.x * 256 + threadIdx.x;
    if (i < n) p[i] = 0;
}

// ---------------------------------------------------------------------------
// x f32 -> bf16
__global__ void k_cvt(const float* __restrict__ x, ushort* __restrict__ xb,
                      int n4) {
    int i = blockIdx.x * 256 + threadIdx.x;
    if (i >= n4) return;
    float4 v = ((const float4*)x)[i];
    uint2 r;
    r.x = (uint)f2bf(v.x) | ((uint)f2bf(v.y) << 16);
    r.y = (uint)f2bf(v.z) | ((uint)f2bf(v.w) << 16);
    ((uint2*)xb)[i] = r;
}

// W (K x N f32) -> transposed split planes Wh/Wl (N x K bf16), 6 matrices.
__global__ void k_wprep(const float* __restrict__ W1,
                        const float* __restrict__ W2, ushort* __restrict__ Wh,
                        ushort* __restrict__ Wl) {
    int i = blockIdx.x * 256 + threadIdx.x;
    if (i >= 6 * 16384) return;
    int l = i >> 14;
    int r = i & 16383;
    int n = r >> 7, k = r & 127;
    const float* W = (l < 3) ? (W1 + l * 16384) : (W2 + (l - 3) * 16384);
    float w = W[k * 128 + n];
    ushort h = f2bf(w);
    Wh[i] = h;
    Wl[i] = f2bf(w - bf2f(h));
}

// ---------------------------------------------------------------------------
// CSR build.  4 edges per thread: batch loads, keep 4 atomics in flight.
__global__ void k_hist(const int* __restrict__ dst, int* __restrict__ cnt,
                       int nE) {
    int t = blockIdx.x * 1024 + threadIdx.x;
    int d[4];
#pragma unroll
    for (int k = 0; k < 4; ++k) {
        int e = t + k * 256;
        d[k] = (e < nE) ? dst[e] : -1;
    }
#pragma unroll
    for (int k = 0; k < 4; ++k)
        if (d[k] >= 0) atomicAdd(&cnt[d[k]], 1);
}

__global__ void k_scanA(const int* __restrict__ cnt, int* __restrict__ excl,
                        int* __restrict__ bsum, int n) {
    __shared__ int s[256];
    int t = threadIdx.x, i = blockIdx.x * 256 + t;
    int v = (i < n) ? cnt[i] : 0;
    s[t] = v;
    __syncthreads();
#pragma unroll
    for (int o = 1; o < 256; o <<= 1) {
        int a = (t >= o) ? s[t - o] : 0;
        __syncthreads();
        s[t] += a;
        __syncthreads();
    }
    if (i < n) excl[i] = s[t] - v;
    if (t == 255) bsum[blockIdx.x] = s[255];
}

__global__ void k_scanB(int* bsum, int nB) {
    __shared__ int s[512];
    int t = threadIdx.x;
    int v = (t < nB) ? bsum[t] : 0;
    s[t] = v;
    __syncthreads();
#pragma unroll
    for (int o = 1; o < 512; o <<= 1) {
        int a = (t >= o) ? s[t - o] : 0;
        __syncthreads();
        s[t] += a;
        __syncthreads();
    }
    if (t < nB) bsum[t] = s[t] - v;
}

__global__ void k_scanC(int* __restrict__ rowptr, int* __restrict__ cursor,
                        const int* __restrict__ bsum, int n, int total) {
    int t = threadIdx.x, i = blockIdx.x * 256 + t;
    if (i < n) {
        int r = rowptr[i] + bsum[blockIdx.x];
        rowptr[i] = r;
        cursor[i] = r;
    } else if (i == n) {
        rowptr[n] = total;
    }
}

__global__ void k_fill(const int* __restrict__ src, const int* __restrict__ dst,
                       int* __restrict__ cursor, int* __restrict__ srcs,
                       int nE) {
    int t = blockIdx.x * 1024 + threadIdx.x;
    int d[4], s[4], p[4];
#pragma unroll
    for (int k = 0; k < 4; ++k) {
        int e = t + k * 256;
        bool ok = e < nE;
        d[k] = ok ? dst[e] : -1;
        s[k] = ok ? src[e] : 0;
    }
#pragma unroll
    for (int k = 0; k < 4; ++k)
        if (d[k] >= 0) p[k] = atomicAdd(&cursor[d[k]], 1);
#pragma unroll
    for (int k = 0; k < 4; ++k)
        if (d[k] >= 0) srcs[p[k]] = s[k];
}

// ---------------------------------------------------------------------------
// Gather aggregation: bf16 in, f32 accumulate, f32 out.  Edge loop unrolled
// x4 with independent row loads in flight; two accumulator sets.
__global__ void k_gather(const ushort* __restrict__ h,
                         const int* __restrict__ rowptr,
                         const int* __restrict__ srcs,
                         const float* __restrict__ scale,
                         const float* __restrict__ shift,
                         float* __restrict__ agg, int M) {
    int t = threadIdx.x;
    int node = blockIdx.x * 8 + (t >> 5);
    if (node >= M) return;
    int c = (t & 31) * 4;
    const bool bn = (scale != nullptr);
    float4 sc = make_float4(1.f, 1.f, 1.f, 1.f);
    float4 sh = make_float4(0.f, 0.f, 0.f, 0.f);
    if (bn) {
        sc = *(const float4*)(scale + c);
        sh = *(const float4*)(shift + c);
    }
    int beg = rowptr[node];
    int end = rowptr[node + 1];

    uint2 v = *(const uint2*)(h + (size_t)node * DIM + c);
    float a0 = bflo(v.x), a1 = bfhi(v.x), a2 = bflo(v.y), a3 = bfhi(v.y);
    if (bn) {
        a0 = fmaxf(fmaf(a0, sc.x, sh.x), 0.f);
        a1 = fmaxf(fmaf(a1, sc.y, sh.y), 0.f);
        a2 = fmaxf(fmaf(a2, sc.z, sh.z), 0.f);
        a3 = fmaxf(fmaf(a3, sc.w, sh.w), 0.f);
    }
    float b0 = 0.f, b1 = 0.f, b2 = 0.f, b3 = 0.f;  // second accumulator set

    int j = beg;
    for (; j + 4 <= end; j += 4) {
        int s0 = srcs[j], s1 = srcs[j + 1], s2 = srcs[j + 2], s3 = srcs[j + 3];
        uint2 g0 = *(const uint2*)(h + (size_t)s0 * DIM + c);
        uint2 g1 = *(const uint2*)(h + (size_t)s1 * DIM + c);
        uint2 g2 = *(const uint2*)(h + (size_t)s2 * DIM + c);
        uint2 g3 = *(const uint2*)(h + (size_t)s3 * DIM + c);
        float f0, f1, f2, f3;
        if (bn) {
            f0 = fmaxf(fmaf(bflo(g0.x), sc.x, sh.x), 0.f);
            f1 = fmaxf(fmaf(bfhi(g0.x), sc.y, sh.y), 0.f);
            f2 = fmaxf(fmaf(bflo(g0.y), sc.z, sh.z), 0.f);
            f3 = fmaxf(fmaf(bfhi(g0.y), sc.w, sh.w), 0.f);
            a0 += f0; a1 += f1; a2 += f2; a3 += f3;
            f0 = fmaxf(fmaf(bflo(g1.x), sc.x, sh.x), 0.f);
            f1 = fmaxf(fmaf(bfhi(g1.x), sc.y, sh.y), 0.f);
            f2 = fmaxf(fmaf(bflo(g1.y), sc.z, sh.z), 0.f);
            f3 = fmaxf(fmaf(bfhi(g1.y), sc.w, sh.w), 0.f);
            b0 += f0; b1 += f1; b2 += f2; b3 += f3;
            f0 = fmaxf(fmaf(bflo(g2.x), sc.x, sh.x), 0.f);
            f1 = fmaxf(fmaf(bfhi(g2.x), sc.y, sh.y), 0.f);
            f2 = fmaxf(fmaf(bflo(g2.y), sc.z, sh.z), 0.f);
            f3 = fmaxf(fmaf(bfhi(g2.y), sc.w, sh.w), 0.f);
            a0 += f0; a1 += f1; a2 += f2; a3 += f3;
            f0 = fmaxf(fmaf(bflo(g3.x), sc.x, sh.x), 0.f);
            f1 = fmaxf(fmaf(bfhi(g3.x), sc.y, sh.y), 0.f);
            f2 = fmaxf(fmaf(bflo(g3.y), sc.z, sh.z), 0.f);
            f3 = fmaxf(fmaf(bfhi(g3.y), sc.w, sh.w), 0.f);
            b0 += f0; b1 += f1; b2 += f2; b3 += f3;
        } else {
            a0 += bflo(g0.x); a1 += bfhi(g0.x); a2 += bflo(g0.y); a3 += bfhi(g0.y);
            b0 += bflo(g1.x); b1 += bfhi(g1.x); b2 += bflo(g1.y); b3 += bfhi(g1.y);
            a0 += bflo(g2.x); a1 += bfhi(g2.x); a2 += bflo(g2.y); a3 += bfhi(g2.y);
            b0 += bflo(g3.x); b1 += bfhi(g3.x); b2 += bflo(g3.y); b3 += bfhi(g3.y);
        }
    }
    for (; j < end; ++j) {
        int s = srcs[j];
        uint2 g = *(const uint2*)(h + (size_t)s * DIM + c);
        if (bn) {
            a0 += fmaxf(fmaf(bflo(g.x), sc.x, sh.x), 0.f);
            a1 += fmaxf(fmaf(bfhi(g.x), sc.y, sh.y), 0.f);
            a2 += fmaxf(fmaf(bflo(g.y), sc.z, sh.z), 0.f);
            a3 += fmaxf(fmaf(bfhi(g.y), sc.w, sh.w), 0.f);
        } else {
            a0 += bflo(g.x); a1 += bfhi(g.x); a2 += bflo(g.y); a3 += bfhi(g.y);
        }
    }
    float4 r = make_float4(a0 + b0, a1 + b1, a2 + b2, a3 + b3);
    *(float4*)(agg + (size_t)node * DIM + c) = r;
}

// ---------------------------------------------------------------------------
// Split-bf16 MFMA GEMM (near-f32): C = BNrelu(A) @ W + bias.
__global__ void __launch_bounds__(256, 2) k_gemm(
    const float* __restrict__ A, const ushort* __restrict__ Wh,
    const ushort* __restrict__ Wl, const float* __restrict__ bias,
    const float* __restrict__ scale, const float* __restrict__ shift,
    float* __restrict__ Cf, ushort* __restrict__ Cb,
    float* __restrict__ statSum, float* __restrict__ statSq,
    float* __restrict__ outF, int M) {
    __shared__ char smem[65536];
    char* Ah = smem;            // 128 rows x 256B (swizzled) hi plane
    char* Alo = smem + 32768;   // lo plane

    const int t = threadIdx.x;
    const int w = t >> 6;
    const int lane = t & 63;
    const int rquad = lane >> 4;
    const int rcol = lane & 15;
    const int rowBase = blockIdx.x * 128;

    // ---- stage A: f32 load, optional BNrelu, split to bf16 hi/lo ----
#pragma unroll
    for (int i = 0; i < 16; ++i) {
        int idx = t + i * 256;      // 4096 4-float chunks
        int row = idx >> 5;
        int ch = idx & 31;
        int grow = rowBase + row;
        if (grow >= M) grow = M - 1;
        float4 v = *(const float4*)(A + (size_t)grow * DIM + ch * 4);
        if (scale) {
            int c0 = ch * 4;
            v.x = fmaxf(fmaf(v.x, scale[c0 + 0], shift[c0 + 0]), 0.f);
            v.y = fmaxf(fmaf(v.y, scale[c0 + 1], shift[c0 + 1]), 0.f);
            v.z = fmaxf(fmaf(v.z, scale[c0 + 2], shift[c0 + 2]), 0.f);
            v.w = fmaxf(fmaf(v.w, scale[c0 + 3], shift[c0 + 3]), 0.f);
        }
        ushort h0 = f2bf(v.x), h1 = f2bf(v.y), h2 = f2bf(v.z), h3 = f2bf(v.w);
        ushort l0 = f2bf(v.x - bf2f(h0)), l1 = f2bf(v.y - bf2f(h1));
        ushort l2 = f2bf(v.z - bf2f(h2)), l3 = f2bf(v.w - bf2f(h3));
        uint2 hp, lp;
        hp.x = (uint)h0 | ((uint)h1 << 16);
        hp.y = (uint)h2 | ((uint)h3 << 16);
        lp.x = (uint)l0 | ((uint)l1 << 16);
        lp.y = (uint)l2 | ((uint)l3 << 16);
        *(uint2*)(Ah + SWZ(row, row * 256 + ch * 8)) = hp;
        *(uint2*)(Alo + SWZ(row, row * 256 + ch * 8)) = lp;
    }
    __syncthreads();

    // ---- MFMA main loop ----
    f32x4 acc[2][8];
#pragma unroll
    for (int i = 0; i < 2; ++i)
#pragma unroll
        for (int j = 0; j < 8; ++j) acc[i][j] = (f32x4){0.f, 0.f, 0.f, 0.f};

#pragma unroll
    for (int kc = 0; kc < 4; ++kc) {
        bf16x8 bh[8], bl[8];
#pragma unroll
        for (int j = 0; j < 8; ++j) {
            size_t off = (size_t)(j * 16 + rcol) * DIM + kc * 32 + rquad * 8;
            bh[j] = *(const bf16x8*)(Wh + off);
            bl[j] = *(const bf16x8*)(Wl + off);
        }
        int kb = (kc * 32 + rquad * 8) * 2;
        bf16x8 ah[2], al[2];
#pragma unroll
        for (int i = 0; i < 2; ++i) {
            int row = w * 32 + i * 16 + rcol;
            ah[i] = *(const bf16x8*)(Ah + SWZ(row, row * 256 + kb));
            al[i] = *(const bf16x8*)(Alo + SWZ(row, row * 256 + kb));
        }
#pragma unroll
        for (int i = 0; i < 2; ++i)
#pragma unroll
            for (int j = 0; j < 8; ++j) {
                acc[i][j] = __builtin_amdgcn_mfma_f32_16x16x32_bf16(
                    ah[i], bh[j], acc[i][j], 0, 0, 0);
                acc[i][j] = __builtin_amdgcn_mfma_f32_16x16x32_bf16(
                    al[i], bh[j], acc[i][j], 0, 0, 0);
                acc[i][j] = __builtin_amdgcn_mfma_f32_16x16x32_bf16(
                    ah[i], bl[j], acc[i][j], 0, 0, 0);
            }
    }

    // ---- epilogue ----
    float bc[8];
#pragma unroll
    for (int j = 0; j < 8; ++j) bc[j] = bias[j * 16 + rcol];

    if (outF) {  // fused L2 normalize
#pragma unroll
        for (int i = 0; i < 2; ++i) {
#pragma unroll
            for (int r = 0; r < 4; ++r) {
                int row = rowBase + w * 32 + i * 16 + rquad * 4 + r;
                float o[8];
                float ss = 0.f;
#pragma unroll
                for (int j = 0; j < 8; ++j) {
                    o[j] = acc[i][j][r] + bc[j];
                    ss += o[j] * o[j];
                }
                ss += __shfl_xor(ss, 1);
                ss += __shfl_xor(ss, 2);
                ss += __shfl_xor(ss, 4);
                ss += __shfl_xor(ss, 8);
                float inv = 1.f / fmaxf(sqrtf(ss), 1e-12f);
                if (row < M) {
#pragma unroll
                    for (int j = 0; j < 8; ++j)
                        outF[(size_t)row * DIM + j * 16 + rcol] = o[j] * inv;
                }
            }
        }
        return;
    }

    // stats mode: store (f32 or bf16) + column sum/sumsq
    float csum[8], csq[8];
#pragma unroll
    for (int j = 0; j < 8; ++j) { csum[j] = 0.f; csq[j] = 0.f; }
#pragma unroll
    for (int i = 0; i < 2; ++i) {
#pragma unroll
        for (int r = 0; r < 4; ++r) {
            int row = rowBase + w * 32 + i * 16 + rquad * 4 + r;
            if (row < M) {
#pragma unroll
                for (int j = 0; j < 8; ++j) {
                    float o = acc[i][j][r] + bc[j];
                    if (Cf) Cf[(size_t)row * DIM + j * 16 + rcol] = o;
                    else Cb[(size_t)row * DIM + j * 16 + rcol] = f2bf(o);
                    csum[j] += o;
                    csq[j] += o * o;
                }
            }
        }
    }
#pragma unroll
    for (int j = 0; j < 8; ++j) {
        csum[j] += __shfl_xor(csum[j], 16);
        csum[j] += __shfl_xor(csum[j], 32);
        csq[j] += __shfl_xor(csq[j], 16);
        csq[j] += __shfl_xor(csq[j], 32);
    }
    __syncthreads();  // all LDS reads done; reuse for cross-wave reduce
    float* red = (float*)smem;
    if (lane < 16) {
#pragma unroll
        for (int j = 0; j < 8; ++j) {
            red[w * 128 + j * 16 + rcol] = csum[j];
            red[512 + w * 128 + j * 16 + rcol] = csq[j];
        }
    }
    __syncthreads();
    if (t < 128) {
        float s = red[t] + red[128 + t] + red[256 + t] + red[384 + t];
        float q = red[512 + t] + red[640 + t] + red[768 + t] + red[896 + t];
        atomicAdd(statSum + t, s);
        atomicAdd(statSq + t, q);
    }
}

// ---------------------------------------------------------------------------
// Consumes sum/sq -> scale/shift, then ZEROES sum/sq for the next GEMM.
__global__ void k_bnfin(float* __restrict__ sum, float* __restrict__ sq,
                        const float* __restrict__ g,
                        const float* __restrict__ be,
                        float* __restrict__ scale,
                        float* __restrict__ shift, float invN) {
    int c = threadIdx.x;
    float mu = sum[c] * invN;
    float var = sq[c] * invN - mu * mu;
    float inv = rsqrtf(var + 1e-5f);
    float s = g[c] * inv;
    scale[c] = s;
    shift[c] = be[c] - mu * s;
    sum[c] = 0.f;
    sq[c] = 0.f;
}

// ---------------------------------------------------------------------------
extern "C" void kernel_launch(void* const* d_in, const int* in_sizes, int n_in,
                              void* d_out, int out_size, void* d_ws,
                              size_t ws_size, hipStream_t stream) {
    const float* x = (const float*)d_in[0];
    const int* ei = (const int*)d_in[1];
    const float* W1 = (const float*)d_in[2];
    const float* b1 = (const float*)d_in[3];
    const float* g1 = (const float*)d_in[4];
    const float* be1 = (const float*)d_in[5];
    const float* W2 = (const float*)d_in[6];
    const float* b2 = (const float*)d_in[7];
    const float* g_out = (const float*)d_in[8];
    const float* b_out = (const float*)d_in[9];
    float* out = (float*)d_out;

    const int M = M_NODES;
    const int E = N_EDGES_TOT;
    const size_t NM = (size_t)M * DIM;

    float* AGC = (float*)d_ws;         // f32: gather out / GEMM1 in-place out
    ushort* B0 = (ushort*)(AGC + NM);  // bf16 h buffer (gather input)
    ushort* Wh = B0 + NM;              // 6*16384 bf16 hi
    ushort* Wl = Wh + 6 * 16384;       // 6*16384 bf16 lo
    float* st = (float*)(Wl + 6 * 16384);
    float* sum = st;
    float* sq = st + 128;
    float* sc1 = st + 256;
    float* sh1 = st + 384;
    float* sc2 = st + 512;
    float* sh2 = st + 640;
    int* rowptr = (int*)(st + 768);
    int* cursor = rowptr + (M + 1);
    int* bsum = cursor + M;
    int* srcs = bsum + 512;

    const int* src = ei;
    const int* dst = ei + E;

    const int gemmGrid = (M + 127) / 128;
    const int gathGrid = (M + 7) / 8;
    const int nB = (M + 255) / 256;
    const int edgeGrid4 = (E + 1023) / 1024;
    const float invN = 1.f / (float)M;

    // ---------------- prep: CSR + conversions --------------------
    k_zeroi<<<(M + 255) / 256, 256, 0, stream>>>(cursor, M);
    k_hist<<<edgeGrid4, 256, 0, stream>>>(dst, cursor, E);
    k_scanA<<<nB, 256, 0, stream>>>(cursor, rowptr, bsum, M);
    k_scanB<<<1, 512, 0, stream>>>(bsum, nB);
    k_scanC<<<nB, 256, 0, stream>>>(rowptr, cursor, bsum, M, E);
    k_fill<<<edgeGrid4, 256, 0, stream>>>(src, dst, cursor, srcs, E);
    k_cvt<<<(int)((NM / 4 + 255) / 256), 256, 0, stream>>>(x, B0, (int)(NM / 4));
    k_wprep<<<(6 * 16384 + 255) / 256, 256, 0, stream>>>(W1, W2, Wh, Wl);
    k_zerof<<<1, 256, 0, stream>>>(sum, 256);  // sum+sq; bnfin re-zeroes after

    // ---------------- layer 0 ----------------
    k_gather<<<gathGrid, 256, 0, stream>>>(B0, rowptr, srcs, nullptr, nullptr, AGC, M);
    k_gemm<<<gemmGrid, 256, 0, stream>>>(AGC, Wh, Wl, b1, nullptr, nullptr,
                                         AGC, nullptr, sum, sq, nullptr, M);
    k_bnfin<<<1, 128, 0, stream>>>(sum, sq, g1, be1, sc1, sh1, invN);
    k_gemm<<<gemmGrid, 256, 0, stream>>>(AGC, Wh + 3 * 16384, Wl + 3 * 16384, b2,
                                         sc1, sh1, nullptr, B0, sum, sq, nullptr, M);
    k_bnfin<<<1, 128, 0, stream>>>(sum, sq, g_out, b_out, sc2, sh2, invN);

    // ---------------- layer 1 ----------------
    k_gather<<<gathGrid, 256, 0, stream>>>(B0, rowptr, srcs, sc2, sh2, AGC, M);
    k_gemm<<<gemmGrid, 256, 0, stream>>>(AGC, Wh + 16384, Wl + 16384, b1 + 128,
                                         nullptr, nullptr, AGC, nullptr, sum, sq, nullptr, M);
    k_bnfin<<<1, 128, 0, stream>>>(sum, sq, g1 + 128, be1 + 128, sc1, sh1, invN);
    k_gemm<<<gemmGrid, 256, 0, stream>>>(AGC, Wh + 4 * 16384, Wl + 4 * 16384, b2 + 128,
                                         sc1, sh1, nullptr, B0, sum, sq, nullptr, M);
    k_bnfin<<<1, 128, 0, stream>>>(sum, sq, g_out + 128, b_out + 128, sc2, sh2, invN);

    // ---------------- layer 2 ----------------
    k_gather<<<gathGrid, 256, 0, stream>>>(B0, rowptr, srcs, sc2, sh2, AGC, M);
    k_gemm<<<gemmGrid, 256, 0, stream>>>(AGC, Wh + 2 * 16384, Wl + 2 * 16384, b1 + 256,
                                         nullptr, nullptr, AGC, nullptr, sum, sq, nullptr, M);
    k_bnfin<<<1, 128, 0, stream>>>(sum, sq, g1 + 256, be1 + 256, sc1, sh1, invN);
    // final GEMM: fused L2 normalize, f32 straight to d_out
    k_gemm<<<gemmGrid, 256, 0, stream>>>(AGC, Wh + 5 * 16384, Wl + 5 * 16384, b2 + 256,
                                         sc1, sh1, nullptr, nullptr, nullptr, nullptr, out, M);
}

// Round 6
// 736.740 us; speedup vs baseline: 11.6185x; 1.0468x over previous
//
#include <hip/hip_runtime.h>

#define M_NODES 100000
#define DIM 128
#define N_EDGES_TOT 1600000

typedef unsigned int uint;
typedef unsigned short ushort;
typedef __attribute__((ext_vector_type(8))) short bf16x8;
typedef __attribute__((ext_vector_type(4))) float f32x4;

__device__ __forceinline__ float bflo(uint u) { return __uint_as_float(u << 16); }
__device__ __forceinline__ float bfhi(uint u) { return __uint_as_float(u & 0xffff0000u); }
__device__ __forceinline__ float bf2f(ushort h) { return __uint_as_float(((uint)h) << 16); }
__device__ __forceinline__ ushort f2bf(float f) {
    uint u = __float_as_uint(f);
    return (ushort)((u + 0x7fffu + ((u >> 16) & 1u)) >> 16);
}
// LDS byte-offset XOR swizzle: breaks 16-way bank conflict on 256B-row tiles.
__device__ __forceinline__ int SWZ(int row, int byte) {
    return byte ^ ((row & 7) << 4);
}

// ---------------------------------------------------------------------------
__global__ void k_zerof(float* p, int n) {
    int i = blockIdx.x * 256 + threadIdx.x;
    if (i < n) p[i] = 0.f;
}
__global__ void k_zeroi(int* p, int n) {
    int i = blockIdx.x * 256 + threadIdx.x;
    if (i < n) p[i] = 0;
}

// ---------------------------------------------------------------------------
// x f32 -> bf16
__global__ void k_cvt(const float* __restrict__ x, ushort* __restrict__ xb,
                      int n4) {
    int i = blockIdx.x * 256 + threadIdx.x;
    if (i >= n4) return;
    float4 v = ((const float4*)x)[i];
    uint2 r;
    r.x = (uint)f2bf(v.x) | ((uint)f2bf(v.y) << 16);
    r.y = (uint)f2bf(v.z) | ((uint)f2bf(v.w) << 16);
    ((uint2*)xb)[i] = r;
}

// W (K x N f32) -> transposed split planes Wh/Wl (N x K bf16), 6 matrices.
__global__ void k_wprep(const float* __restrict__ W1,
                        const float* __restrict__ W2, ushort* __restrict__ Wh,
                        ushort* __restrict__ Wl) {
    int i = blockIdx.x * 256 + threadIdx.x;
    if (i >= 6 * 16384) return;
    int l = i >> 14;
    int r = i & 16383;
    int n = r >> 7, k = r & 127;
    const float* W = (l < 3) ? (W1 + l * 16384) : (W2 + (l - 3) * 16384);
    float w = W[k * 128 + n];
    ushort h = f2bf(w);
    Wh[i] = h;
    Wl[i] = f2bf(w - bf2f(h));
}

// ---------------------------------------------------------------------------
// CSR build.
__global__ void k_hist(const int* __restrict__ dst, int* __restrict__ cnt,
                       int nE) {
    int t = blockIdx.x * 1024 + threadIdx.x;
    int d[4];
#pragma unroll
    for (int k = 0; k < 4; ++k) {
        int e = t + k * 256;
        d[k] = (e < nE) ? dst[e] : -1;
    }
#pragma unroll
    for (int k = 0; k < 4; ++k)
        if (d[k] >= 0) atomicAdd(&cnt[d[k]], 1);
}

__global__ void k_scanA(const int* __restrict__ cnt, int* __restrict__ excl,
                        int* __restrict__ bsum, int n) {
    __shared__ int s[256];
    int t = threadIdx.x, i = blockIdx.x * 256 + t;
    int v = (i < n) ? cnt[i] : 0;
    s[t] = v;
    __syncthreads();
#pragma unroll
    for (int o = 1; o < 256; o <<= 1) {
        int a = (t >= o) ? s[t - o] : 0;
        __syncthreads();
        s[t] += a;
        __syncthreads();
    }
    if (i < n) excl[i] = s[t] - v;
    if (t == 255) bsum[blockIdx.x] = s[255];
}

__global__ void k_scanB(int* bsum, int nB) {
    __shared__ int s[512];
    int t = threadIdx.x;
    int v = (t < nB) ? bsum[t] : 0;
    s[t] = v;
    __syncthreads();
#pragma unroll
    for (int o = 1; o < 512; o <<= 1) {
        int a = (t >= o) ? s[t - o] : 0;
        __syncthreads();
        s[t] += a;
        __syncthreads();
    }
    if (t < nB) bsum[t] = s[t] - v;
}

__global__ void k_scanC(int* __restrict__ rowptr, int* __restrict__ cursor,
                        const int* __restrict__ bsum, int n, int total) {
    int t = threadIdx.x, i = blockIdx.x * 256 + t;
    if (i < n) {
        int r = rowptr[i] + bsum[blockIdx.x];
        rowptr[i] = r;
        cursor[i] = r;
    } else if (i == n) {
        rowptr[n] = total;
    }
}

// XCD-sliced bucket fill: block (chunk = bid>>3, slice = bid&7) processes
// edges in its chunk whose dst lies in slice [slice*12500, +12500).  With
// bid%8 ~ XCD round-robin, each CSR line of srcs is written by ONE XCD ->
// stores merge in that XCD's L2 -> writeback ~6.4 MB instead of ~109 MB.
// Correct regardless of the actual block->XCD mapping (slice is a filter).
__global__ void k_fill(const int* __restrict__ src, const int* __restrict__ dst,
                       int* __restrict__ cursor, int* __restrict__ srcs,
                       int nE) {
    const int slice = blockIdx.x & 7;
    const int chunk = blockIdx.x >> 3;
    const int base = chunk * 2048 + threadIdx.x;
    const int lo = slice * 12500;
    const int hi = lo + 12500;
    int d[8], s[8];
#pragma unroll
    for (int k = 0; k < 8; ++k) {
        int e = base + k * 256;
        d[k] = (e < nE) ? dst[e] : -1;
    }
#pragma unroll
    for (int k = 0; k < 8; ++k) {
        if (d[k] >= lo && d[k] < hi) s[k] = src[base + k * 256];
    }
#pragma unroll
    for (int k = 0; k < 8; ++k) {
        if (d[k] >= lo && d[k] < hi) {
            int p = atomicAdd(&cursor[d[k]], 1);
            srcs[p] = s[k];
        }
    }
}

// ---------------------------------------------------------------------------
// Gather aggregation: bf16 in, f32 accumulate, f32 out.  Edge loop unrolled
// x4 with independent row loads in flight; two accumulator sets.
__global__ void k_gather(const ushort* __restrict__ h,
                         const int* __restrict__ rowptr,
                         const int* __restrict__ srcs,
                         const float* __restrict__ scale,
                         const float* __restrict__ shift,
                         float* __restrict__ agg, int M) {
    int t = threadIdx.x;
    int node = blockIdx.x * 8 + (t >> 5);
    if (node >= M) return;
    int c = (t & 31) * 4;
    const bool bn = (scale != nullptr);
    float4 sc = make_float4(1.f, 1.f, 1.f, 1.f);
    float4 sh = make_float4(0.f, 0.f, 0.f, 0.f);
    if (bn) {
        sc = *(const float4*)(scale + c);
        sh = *(const float4*)(shift + c);
    }
    int beg = rowptr[node];
    int end = rowptr[node + 1];

    uint2 v = *(const uint2*)(h + (size_t)node * DIM + c);
    float a0 = bflo(v.x), a1 = bfhi(v.x), a2 = bflo(v.y), a3 = bfhi(v.y);
    if (bn) {
        a0 = fmaxf(fmaf(a0, sc.x, sh.x), 0.f);
        a1 = fmaxf(fmaf(a1, sc.y, sh.y), 0.f);
        a2 = fmaxf(fmaf(a2, sc.z, sh.z), 0.f);
        a3 = fmaxf(fmaf(a3, sc.w, sh.w), 0.f);
    }
    float b0 = 0.f, b1 = 0.f, b2 = 0.f, b3 = 0.f;  // second accumulator set

    int j = beg;
    for (; j + 4 <= end; j += 4) {
        int s0 = srcs[j], s1 = srcs[j + 1], s2 = srcs[j + 2], s3 = srcs[j + 3];
        uint2 g0 = *(const uint2*)(h + (size_t)s0 * DIM + c);
        uint2 g1 = *(const uint2*)(h + (size_t)s1 * DIM + c);
        uint2 g2 = *(const uint2*)(h + (size_t)s2 * DIM + c);
        uint2 g3 = *(const uint2*)(h + (size_t)s3 * DIM + c);
        float f0, f1, f2, f3;
        if (bn) {
            f0 = fmaxf(fmaf(bflo(g0.x), sc.x, sh.x), 0.f);
            f1 = fmaxf(fmaf(bfhi(g0.x), sc.y, sh.y), 0.f);
            f2 = fmaxf(fmaf(bflo(g0.y), sc.z, sh.z), 0.f);
            f3 = fmaxf(fmaf(bfhi(g0.y), sc.w, sh.w), 0.f);
            a0 += f0; a1 += f1; a2 += f2; a3 += f3;
            f0 = fmaxf(fmaf(bflo(g1.x), sc.x, sh.x), 0.f);
            f1 = fmaxf(fmaf(bfhi(g1.x), sc.y, sh.y), 0.f);
            f2 = fmaxf(fmaf(bflo(g1.y), sc.z, sh.z), 0.f);
            f3 = fmaxf(fmaf(bfhi(g1.y), sc.w, sh.w), 0.f);
            b0 += f0; b1 += f1; b2 += f2; b3 += f3;
            f0 = fmaxf(fmaf(bflo(g2.x), sc.x, sh.x), 0.f);
            f1 = fmaxf(fmaf(bfhi(g2.x), sc.y, sh.y), 0.f);
            f2 = fmaxf(fmaf(bflo(g2.y), sc.z, sh.z), 0.f);
            f3 = fmaxf(fmaf(bfhi(g2.y), sc.w, sh.w), 0.f);
            a0 += f0; a1 += f1; a2 += f2; a3 += f3;
            f0 = fmaxf(fmaf(bflo(g3.x), sc.x, sh.x), 0.f);
            f1 = fmaxf(fmaf(bfhi(g3.x), sc.y, sh.y), 0.f);
            f2 = fmaxf(fmaf(bflo(g3.y), sc.z, sh.z), 0.f);
            f3 = fmaxf(fmaf(bfhi(g3.y), sc.w, sh.w), 0.f);
            b0 += f0; b1 += f1; b2 += f2; b3 += f3;
        } else {
            a0 += bflo(g0.x); a1 += bfhi(g0.x); a2 += bflo(g0.y); a3 += bfhi(g0.y);
            b0 += bflo(g1.x); b1 += bfhi(g1.x); b2 += bflo(g1.y); b3 += bfhi(g1.y);
            a0 += bflo(g2.x); a1 += bfhi(g2.x); a2 += bflo(g2.y); a3 += bfhi(g2.y);
            b0 += bflo(g3.x); b1 += bfhi(g3.x); b2 += bflo(g3.y); b3 += bfhi(g3.y);
        }
    }
    for (; j < end; ++j) {
        int s = srcs[j];
        uint2 g = *(const uint2*)(h + (size_t)s * DIM + c);
        if (bn) {
            a0 += fmaxf(fmaf(bflo(g.x), sc.x, sh.x), 0.f);
            a1 += fmaxf(fmaf(bfhi(g.x), sc.y, sh.y), 0.f);
            a2 += fmaxf(fmaf(bflo(g.y), sc.z, sh.z), 0.f);
            a3 += fmaxf(fmaf(bfhi(g.y), sc.w, sh.w), 0.f);
        } else {
            a0 += bflo(g.x); a1 += bfhi(g.x); a2 += bflo(g.y); a3 += bfhi(g.y);
        }
    }
    float4 r = make_float4(a0 + b0, a1 + b1, a2 + b2, a3 + b3);
    *(float4*)(agg + (size_t)node * DIM + c) = r;
}

// ---------------------------------------------------------------------------
// Split-bf16 MFMA GEMM (near-f32): C = BNrelu(A) @ W + bias.
__global__ void __launch_bounds__(256, 2) k_gemm(
    const float* __restrict__ A, const ushort* __restrict__ Wh,
    const ushort* __restrict__ Wl, const float* __restrict__ bias,
    const float* __restrict__ scale, const float* __restrict__ shift,
    float* __restrict__ Cf, ushort* __restrict__ Cb,
    float* __restrict__ statSum, float* __restrict__ statSq,
    float* __restrict__ outF, int M) {
    __shared__ char smem[65536];
    char* Ah = smem;            // 128 rows x 256B (swizzled) hi plane
    char* Alo = smem + 32768;   // lo plane

    const int t = threadIdx.x;
    const int w = t >> 6;
    const int lane = t & 63;
    const int rquad = lane >> 4;
    const int rcol = lane & 15;
    const int rowBase = blockIdx.x * 128;

    // ---- stage A: f32 load, optional BNrelu, split to bf16 hi/lo ----
#pragma unroll
    for (int i = 0; i < 16; ++i) {
        int idx = t + i * 256;      // 4096 4-float chunks
        int row = idx >> 5;
        int ch = idx & 31;
        int grow = rowBase + row;
        if (grow >= M) grow = M - 1;
        float4 v = *(const float4*)(A + (size_t)grow * DIM + ch * 4);
        if (scale) {
            int c0 = ch * 4;
            v.x = fmaxf(fmaf(v.x, scale[c0 + 0], shift[c0 + 0]), 0.f);
            v.y = fmaxf(fmaf(v.y, scale[c0 + 1], shift[c0 + 1]), 0.f);
            v.z = fmaxf(fmaf(v.z, scale[c0 + 2], shift[c0 + 2]), 0.f);
            v.w = fmaxf(fmaf(v.w, scale[c0 + 3], shift[c0 + 3]), 0.f);
        }
        ushort h0 = f2bf(v.x), h1 = f2bf(v.y), h2 = f2bf(v.z), h3 = f2bf(v.w);
        ushort l0 = f2bf(v.x - bf2f(h0)), l1 = f2bf(v.y - bf2f(h1));
        ushort l2 = f2bf(v.z - bf2f(h2)), l3 = f2bf(v.w - bf2f(h3));
        uint2 hp, lp;
        hp.x = (uint)h0 | ((uint)h1 << 16);
        hp.y = (uint)h2 | ((uint)h3 << 16);
        lp.x = (uint)l0 | ((uint)l1 << 16);
        lp.y = (uint)l2 | ((uint)l3 << 16);
        *(uint2*)(Ah + SWZ(row, row * 256 + ch * 8)) = hp;
        *(uint2*)(Alo + SWZ(row, row * 256 + ch * 8)) = lp;
    }
    __syncthreads();

    // ---- MFMA main loop ----
    f32x4 acc[2][8];
#pragma unroll
    for (int i = 0; i < 2; ++i)
#pragma unroll
        for (int j = 0; j < 8; ++j) acc[i][j] = (f32x4){0.f, 0.f, 0.f, 0.f};

#pragma unroll
    for (int kc = 0; kc < 4; ++kc) {
        bf16x8 bh[8], bl[8];
#pragma unroll
        for (int j = 0; j < 8; ++j) {
            size_t off = (size_t)(j * 16 + rcol) * DIM + kc * 32 + rquad * 8;
            bh[j] = *(const bf16x8*)(Wh + off);
            bl[j] = *(const bf16x8*)(Wl + off);
        }
        int kb = (kc * 32 + rquad * 8) * 2;
        bf16x8 ah[2], al[2];
#pragma unroll
        for (int i = 0; i < 2; ++i) {
            int row = w * 32 + i * 16 + rcol;
            ah[i] = *(const bf16x8*)(Ah + SWZ(row, row * 256 + kb));
            al[i] = *(const bf16x8*)(Alo + SWZ(row, row * 256 + kb));
        }
#pragma unroll
        for (int i = 0; i < 2; ++i)
#pragma unroll
            for (int j = 0; j < 8; ++j) {
                acc[i][j] = __builtin_amdgcn_mfma_f32_16x16x32_bf16(
                    ah[i], bh[j], acc[i][j], 0, 0, 0);
                acc[i][j] = __builtin_amdgcn_mfma_f32_16x16x32_bf16(
                    al[i], bh[j], acc[i][j], 0, 0, 0);
                acc[i][j] = __builtin_amdgcn_mfma_f32_16x16x32_bf16(
                    ah[i], bl[j], acc[i][j], 0, 0, 0);
            }
    }

    // ---- epilogue ----
    float bc[8];
#pragma unroll
    for (int j = 0; j < 8; ++j) bc[j] = bias[j * 16 + rcol];

    if (outF) {  // fused L2 normalize
#pragma unroll
        for (int i = 0; i < 2; ++i) {
#pragma unroll
            for (int r = 0; r < 4; ++r) {
                int row = rowBase + w * 32 + i * 16 + rquad * 4 + r;
                float o[8];
                float ss = 0.f;
#pragma unroll
                for (int j = 0; j < 8; ++j) {
                    o[j] = acc[i][j][r] + bc[j];
                    ss += o[j] * o[j];
                }
                ss += __shfl_xor(ss, 1);
                ss += __shfl_xor(ss, 2);
                ss += __shfl_xor(ss, 4);
                ss += __shfl_xor(ss, 8);
                float inv = 1.f / fmaxf(sqrtf(ss), 1e-12f);
                if (row < M) {
#pragma unroll
                    for (int j = 0; j < 8; ++j)
                        outF[(size_t)row * DIM + j * 16 + rcol] = o[j] * inv;
                }
            }
        }
        return;
    }

    // stats mode: store (f32 or bf16) + column sum/sumsq
    float csum[8], csq[8];
#pragma unroll
    for (int j = 0; j < 8; ++j) { csum[j] = 0.f; csq[j] = 0.f; }
#pragma unroll
    for (int i = 0; i < 2; ++i) {
#pragma unroll
        for (int r = 0; r < 4; ++r) {
            int row = rowBase + w * 32 + i * 16 + rquad * 4 + r;
            if (row < M) {
#pragma unroll
                for (int j = 0; j < 8; ++j) {
                    float o = acc[i][j][r] + bc[j];
                    if (Cf) Cf[(size_t)row * DIM + j * 16 + rcol] = o;
                    else Cb[(size_t)row * DIM + j * 16 + rcol] = f2bf(o);
                    csum[j] += o;
                    csq[j] += o * o;
                }
            }
        }
    }
#pragma unroll
    for (int j = 0; j < 8; ++j) {
        csum[j] += __shfl_xor(csum[j], 16);
        csum[j] += __shfl_xor(csum[j], 32);
        csq[j] += __shfl_xor(csq[j], 16);
        csq[j] += __shfl_xor(csq[j], 32);
    }
    __syncthreads();  // all LDS reads done; reuse for cross-wave reduce
    float* red = (float*)smem;
    if (lane < 16) {
#pragma unroll
        for (int j = 0; j < 8; ++j) {
            red[w * 128 + j * 16 + rcol] = csum[j];
            red[512 + w * 128 + j * 16 + rcol] = csq[j];
        }
    }
    __syncthreads();
    if (t < 128) {
        float s = red[t] + red[128 + t] + red[256 + t] + red[384 + t];
        float q = red[512 + t] + red[640 + t] + red[768 + t] + red[896 + t];
        atomicAdd(statSum + t, s);
        atomicAdd(statSq + t, q);
    }
}

// ---------------------------------------------------------------------------
// Consumes sum/sq -> scale/shift, then ZEROES sum/sq for the next GEMM.
__global__ void k_bnfin(float* __restrict__ sum, float* __restrict__ sq,
                        const float* __restrict__ g,
                        const float* __restrict__ be,
                        float* __restrict__ scale,
                        float* __restrict__ shift, float invN) {
    int c = threadIdx.x;
    float mu = sum[c] * invN;
    float var = sq[c] * invN - mu * mu;
    float inv = rsqrtf(var + 1e-5f);
    float s = g[c] * inv;
    scale[c] = s;
    shift[c] = be[c] - mu * s;
    sum[c] = 0.f;
    sq[c] = 0.f;
}

// ---------------------------------------------------------------------------
extern "C" void kernel_launch(void* const* d_in, const int* in_sizes, int n_in,
                              void* d_out, int out_size, void* d_ws,
                              size_t ws_size, hipStream_t stream) {
    const float* x = (const float*)d_in[0];
    const int* ei = (const int*)d_in[1];
    const float* W1 = (const float*)d_in[2];
    const float* b1 = (const float*)d_in[3];
    const float* g1 = (const float*)d_in[4];
    const float* be1 = (const float*)d_in[5];
    const float* W2 = (const float*)d_in[6];
    const float* b2 = (const float*)d_in[7];
    const float* g_out = (const float*)d_in[8];
    const float* b_out = (const float*)d_in[9];
    float* out = (float*)d_out;

    const int M = M_NODES;
    const int E = N_EDGES_TOT;
    const size_t NM = (size_t)M * DIM;

    float* AGC = (float*)d_ws;         // f32: gather out / GEMM1 in-place out
    ushort* B0 = (ushort*)(AGC + NM);  // bf16 h buffer (gather input)
    ushort* Wh = B0 + NM;              // 6*16384 bf16 hi
    ushort* Wl = Wh + 6 * 16384;       // 6*16384 bf16 lo
    float* st = (float*)(Wl + 6 * 16384);
    float* sum = st;
    float* sq = st + 128;
    float* sc1 = st + 256;
    float* sh1 = st + 384;
    float* sc2 = st + 512;
    float* sh2 = st + 640;
    int* rowptr = (int*)(st + 768);
    int* cursor = rowptr + (M + 1);
    int* bsum = cursor + M;
    int* srcs = bsum + 512;

    const int* src = ei;
    const int* dst = ei + E;

    const int gemmGrid = (M + 127) / 128;
    const int gathGrid = (M + 7) / 8;
    const int nB = (M + 255) / 256;
    const int edgeGrid4 = (E + 1023) / 1024;
    const int fillGrid = ((E + 2047) / 2048) * 8;  // chunks x 8 XCD slices
    const float invN = 1.f / (float)M;

    // ---------------- prep: CSR + conversions --------------------
    k_zeroi<<<(M + 255) / 256, 256, 0, stream>>>(cursor, M);
    k_hist<<<edgeGrid4, 256, 0, stream>>>(dst, cursor, E);
    k_scanA<<<nB, 256, 0, stream>>>(cursor, rowptr, bsum, M);
    k_scanB<<<1, 512, 0, stream>>>(bsum, nB);
    k_scanC<<<nB, 256, 0, stream>>>(rowptr, cursor, bsum, M, E);
    k_fill<<<fillGrid, 256, 0, stream>>>(src, dst, cursor, srcs, E);
    k_cvt<<<(int)((NM / 4 + 255) / 256), 256, 0, stream>>>(x, B0, (int)(NM / 4));
    k_wprep<<<(6 * 16384 + 255) / 256, 256, 0, stream>>>(W1, W2, Wh, Wl);
    k_zerof<<<1, 256, 0, stream>>>(sum, 256);  // sum+sq; bnfin re-zeroes after

    // ---------------- layer 0 ----------------
    k_gather<<<gathGrid, 256, 0, stream>>>(B0, rowptr, srcs, nullptr, nullptr, AGC, M);
    k_gemm<<<gemmGrid, 256, 0, stream>>>(AGC, Wh, Wl, b1, nullptr, nullptr,
                                         AGC, nullptr, sum, sq, nullptr, M);
    k_bnfin<<<1, 128, 0, stream>>>(sum, sq, g1, be1, sc1, sh1, invN);
    k_gemm<<<gemmGrid, 256, 0, stream>>>(AGC, Wh + 3 * 16384, Wl + 3 * 16384, b2,
                                         sc1, sh1, nullptr, B0, sum, sq, nullptr, M);
    k_bnfin<<<1, 128, 0, stream>>>(sum, sq, g_out, b_out, sc2, sh2, invN);

    // ---------------- layer 1 ----------------
    k_gather<<<gathGrid, 256, 0, stream>>>(B0, rowptr, srcs, sc2, sh2, AGC, M);
    k_gemm<<<gemmGrid, 256, 0, stream>>>(AGC, Wh + 16384, Wl + 16384, b1 + 128,
                                         nullptr, nullptr, AGC, nullptr, sum, sq, nullptr, M);
    k_bnfin<<<1, 128, 0, stream>>>(sum, sq, g1 + 128, be1 + 128, sc1, sh1, invN);
    k_gemm<<<gemmGrid, 256, 0, stream>>>(AGC, Wh + 4 * 16384, Wl + 4 * 16384, b2 + 128,
                                         sc1, sh1, nullptr, B0, sum, sq, nullptr, M);
    k_bnfin<<<1, 128, 0, stream>>>(sum, sq, g_out + 128, b_out + 128, sc2, sh2, invN);

    // ---------------- layer 2 ----------------
    k_gather<<<gathGrid, 256, 0, stream>>>(B0, rowptr, srcs, sc2, sh2, AGC, M);
    k_gemm<<<gemmGrid, 256, 0, stream>>>(AGC, Wh + 2 * 16384, Wl + 2 * 16384, b1 + 256,
                                         nullptr, nullptr, AGC, nullptr, sum, sq, nullptr, M);
    k_bnfin<<<1, 128, 0, stream>>>(sum, sq, g1 + 256, be1 + 256, sc1, sh1, invN);
    // final GEMM: fused L2 normalize, f32 straight to d_out
    k_gemm<<<gemmGrid, 256, 0, stream>>>(AGC, Wh + 5 * 16384, Wl + 5 * 16384, b2 + 256,
                                         sc1, sh1, nullptr, nullptr, nullptr, nullptr, out, M);
}

// Round 7
// 630.691 us; speedup vs baseline: 13.5722x; 1.1681x over previous
//
#include <hip/hip_runtime.h>

#define M_NODES 100000
#define DIM 128
#define N_EDGES_TOT 1600000
#define NBKT 256
#define NPB 391      // nodes per bucket; 256*391 = 100096 >= 100000
#define BKT_CAP 8192 // LDS staging capacity (mean bucket = 6250 edges)

typedef unsigned int uint;
typedef unsigned short ushort;
typedef __attribute__((ext_vector_type(8))) short bf16x8;
typedef __attribute__((ext_vector_type(4))) float f32x4;

__device__ __forceinline__ float bflo(uint u) { return __uint_as_float(u << 16); }
__device__ __forceinline__ float bfhi(uint u) { return __uint_as_float(u & 0xffff0000u); }
__device__ __forceinline__ float bf2f(ushort h) { return __uint_as_float(((uint)h) << 16); }
__device__ __forceinline__ ushort f2bf(float f) {
    uint u = __float_as_uint(f);
    return (ushort)((u + 0x7fffu + ((u >> 16) & 1u)) >> 16);
}
// LDS byte-offset XOR swizzle: breaks 16-way bank conflict on 256B-row tiles.
__device__ __forceinline__ int SWZ(int row, int byte) {
    return byte ^ ((row & 7) << 4);
}

// ---------------------------------------------------------------------------
__global__ void k_zerof(float* p, int n) {
    int i = blockIdx.x * 256 + threadIdx.x;
    if (i < n) p[i] = 0.f;
}

// ---------------------------------------------------------------------------
// x f32 -> bf16
__global__ void k_cvt(const float* __restrict__ x, ushort* __restrict__ xb,
                      int n4) {
    int i = blockIdx.x * 256 + threadIdx.x;
    if (i >= n4) return;
    float4 v = ((const float4*)x)[i];
    uint2 r;
    r.x = (uint)f2bf(v.x) | ((uint)f2bf(v.y) << 16);
    r.y = (uint)f2bf(v.z) | ((uint)f2bf(v.w) << 16);
    ((uint2*)xb)[i] = r;
}

// W (K x N f32) -> transposed split planes Wh/Wl (N x K bf16), 6 matrices.
__global__ void k_wprep(const float* __restrict__ W1,
                        const float* __restrict__ W2, ushort* __restrict__ Wh,
                        ushort* __restrict__ Wl) {
    int i = blockIdx.x * 256 + threadIdx.x;
    if (i >= 6 * 16384) return;
    int l = i >> 14;
    int r = i & 16383;
    int n = r >> 7, k = r & 127;
    const float* W = (l < 3) ? (W1 + l * 16384) : (W2 + (l - 3) * 16384);
    float w = W[k * 128 + n];
    ushort h = f2bf(w);
    Wh[i] = h;
    Wl[i] = f2bf(w - bf2f(h));
}

// ---------------------------------------------------------------------------
// CSR build, bucket-radix, no global atomics.
// Pass A: per-chunk LDS histogram over 256 buckets -> cntM[bucket][chunk].
__global__ void k_bhist(const int* __restrict__ dst, int* __restrict__ cntM,
                        int nE, int nChunks) {
    __shared__ int h[NBKT];
    const int chunk = blockIdx.x, t = threadIdx.x;
    h[t] = 0;
    __syncthreads();
    const int e0 = chunk * 2048;
#pragma unroll
    for (int k = 0; k < 8; ++k) {
        int e = e0 + k * 256 + t;
        if (e < nE) atomicAdd(&h[dst[e] / NPB], 1);
    }
    __syncthreads();
    cntM[t * nChunks + chunk] = h[t];
}

// In-place block scan (256/block) + block sums.
__global__ void k_scanA(int* __restrict__ cnt, int* __restrict__ bsum, int n) {
    __shared__ int s[256];
    int t = threadIdx.x, i = blockIdx.x * 256 + t;
    int v = (i < n) ? cnt[i] : 0;
    s[t] = v;
    __syncthreads();
#pragma unroll
    for (int o = 1; o < 256; o <<= 1) {
        int a = (t >= o) ? s[t - o] : 0;
        __syncthreads();
        s[t] += a;
        __syncthreads();
    }
    if (i < n) cnt[i] = s[t] - v;
    if (t == 255) bsum[blockIdx.x] = s[255];
}

// Scan of up to 1024 block sums, single block.
__global__ void k_scanB(int* bsum, int nB) {
    __shared__ int s[1024];
    int t = threadIdx.x;
    int v = (t < nB) ? bsum[t] : 0;
    s[t] = v;
    __syncthreads();
#pragma unroll
    for (int o = 1; o < 1024; o <<= 1) {
        int a = (t >= o) ? s[t - o] : 0;
        __syncthreads();
        s[t] += a;
        __syncthreads();
    }
    if (t < nB) bsum[t] = s[t] - v;
}

__global__ void k_scanC(int* __restrict__ excl, const int* __restrict__ bsum) {
    int i = blockIdx.x * 256 + threadIdx.x;
    excl[i] += bsum[blockIdx.x];
}

// Pass C: scatter (dst,src) pairs into bucket-sorted order.  Per-block base
// offsets come from the exact scan; LDS atomics hand out unique positions.
// A (bucket,chunk) run is ~8 pairs = 64B -> near-full-line writes.
__global__ void k_pairs(const int* __restrict__ src, const int* __restrict__ dst,
                        const int* __restrict__ exclM, int2* __restrict__ pairs,
                        int nE, int nChunks) {
    __shared__ int base[NBKT];
    const int chunk = blockIdx.x, t = threadIdx.x;
    base[t] = exclM[t * nChunks + chunk];
    __syncthreads();
    const int e0 = chunk * 2048;
#pragma unroll
    for (int k = 0; k < 8; ++k) {
        int e = e0 + k * 256 + t;
        if (e < nE) {
            int d = dst[e];
            int pos = atomicAdd(&base[d / NPB], 1);
            pairs[pos] = make_int2(d, src[e]);
        }
    }
}

// Pass D: one block per bucket.  Per-node count + scan in LDS -> rowptr;
// stage srcs in LDS and stream out linearly (each line written once).
__global__ void k_csrD(const int2* __restrict__ pairs,
                       const int* __restrict__ exclM, int nChunks,
                       int* __restrict__ rowptr, int* __restrict__ srcs,
                       int nE) {
    __shared__ int cnt[512];
    __shared__ int scn[512];
    __shared__ int sl[BKT_CAP];
    const int b = blockIdx.x, t = threadIdx.x;
    const int base = exclM[b * nChunks];
    const int next = (b == NBKT - 1) ? nE : exclM[(b + 1) * nChunks];
    const int count = next - base;
    const int nodeBase = b * NPB;
    const int nNodes = min(NPB, M_NODES - nodeBase);
    cnt[t] = 0;
    cnt[t + 256] = 0;
    __syncthreads();
    for (int i = t; i < count; i += 256)
        atomicAdd(&cnt[pairs[base + i].x - nodeBase], 1);
    __syncthreads();
    scn[t] = cnt[t];
    scn[t + 256] = cnt[t + 256];
    __syncthreads();
#pragma unroll
    for (int o = 1; o < 512; o <<= 1) {
        int a0 = (t >= o) ? scn[t - o] : 0;
        int a1 = scn[t + 256 - o];  // t+256 >= o always (o <= 256)
        __syncthreads();
        scn[t] += a0;
        scn[t + 256] += a1;
        __syncthreads();
    }
    int o0 = scn[t] - cnt[t];          // exclusive offsets (node-local)
    int o1 = scn[t + 256] - cnt[t + 256];
    __syncthreads();
    cnt[t] = o0;                        // cnt[] becomes fill cursor
    cnt[t + 256] = o1;
    if (t < nNodes) rowptr[nodeBase + t] = base + o0;
    if (t + 256 < nNodes) rowptr[nodeBase + t + 256] = base + o1;
    if (b == 0 && t == 0) rowptr[M_NODES] = nE;
    __syncthreads();
    const bool inLds = (count <= BKT_CAP);
    for (int i = t; i < count; i += 256) {
        int2 p = pairs[base + i];
        int pos = atomicAdd(&cnt[p.x - nodeBase], 1);
        if (inLds) sl[pos] = p.y;
        else srcs[base + pos] = p.y;
    }
    __syncthreads();
    if (inLds)
        for (int i = t; i < count; i += 256) srcs[base + i] = sl[i];
}

// ---------------------------------------------------------------------------
// Gather aggregation: bf16 in, f32 accumulate, f32 out.  Edge loop unrolled
// x4 with independent row loads in flight; two accumulator sets.
__global__ void k_gather(const ushort* __restrict__ h,
                         const int* __restrict__ rowptr,
                         const int* __restrict__ srcs,
                         const float* __restrict__ scale,
                         const float* __restrict__ shift,
                         float* __restrict__ agg, int M) {
    int t = threadIdx.x;
    int node = blockIdx.x * 8 + (t >> 5);
    if (node >= M) return;
    int c = (t & 31) * 4;
    const bool bn = (scale != nullptr);
    float4 sc = make_float4(1.f, 1.f, 1.f, 1.f);
    float4 sh = make_float4(0.f, 0.f, 0.f, 0.f);
    if (bn) {
        sc = *(const float4*)(scale + c);
        sh = *(const float4*)(shift + c);
    }
    int beg = rowptr[node];
    int end = rowptr[node + 1];

    uint2 v = *(const uint2*)(h + (size_t)node * DIM + c);
    float a0 = bflo(v.x), a1 = bfhi(v.x), a2 = bflo(v.y), a3 = bfhi(v.y);
    if (bn) {
        a0 = fmaxf(fmaf(a0, sc.x, sh.x), 0.f);
        a1 = fmaxf(fmaf(a1, sc.y, sh.y), 0.f);
        a2 = fmaxf(fmaf(a2, sc.z, sh.z), 0.f);
        a3 = fmaxf(fmaf(a3, sc.w, sh.w), 0.f);
    }
    float b0 = 0.f, b1 = 0.f, b2 = 0.f, b3 = 0.f;  // second accumulator set

    int j = beg;
    for (; j + 4 <= end; j += 4) {
        int s0 = srcs[j], s1 = srcs[j + 1], s2 = srcs[j + 2], s3 = srcs[j + 3];
        uint2 g0 = *(const uint2*)(h + (size_t)s0 * DIM + c);
        uint2 g1 = *(const uint2*)(h + (size_t)s1 * DIM + c);
        uint2 g2 = *(const uint2*)(h + (size_t)s2 * DIM + c);
        uint2 g3 = *(const uint2*)(h + (size_t)s3 * DIM + c);
        float f0, f1, f2, f3;
        if (bn) {
            f0 = fmaxf(fmaf(bflo(g0.x), sc.x, sh.x), 0.f);
            f1 = fmaxf(fmaf(bfhi(g0.x), sc.y, sh.y), 0.f);
            f2 = fmaxf(fmaf(bflo(g0.y), sc.z, sh.z), 0.f);
            f3 = fmaxf(fmaf(bfhi(g0.y), sc.w, sh.w), 0.f);
            a0 += f0; a1 += f1; a2 += f2; a3 += f3;
            f0 = fmaxf(fmaf(bflo(g1.x), sc.x, sh.x), 0.f);
            f1 = fmaxf(fmaf(bfhi(g1.x), sc.y, sh.y), 0.f);
            f2 = fmaxf(fmaf(bflo(g1.y), sc.z, sh.z), 0.f);
            f3 = fmaxf(fmaf(bfhi(g1.y), sc.w, sh.w), 0.f);
            b0 += f0; b1 += f1; b2 += f2; b3 += f3;
            f0 = fmaxf(fmaf(bflo(g2.x), sc.x, sh.x), 0.f);
            f1 = fmaxf(fmaf(bfhi(g2.x), sc.y, sh.y), 0.f);
            f2 = fmaxf(fmaf(bflo(g2.y), sc.z, sh.z), 0.f);
            f3 = fmaxf(fmaf(bfhi(g2.y), sc.w, sh.w), 0.f);
            a0 += f0; a1 += f1; a2 += f2; a3 += f3;
            f0 = fmaxf(fmaf(bflo(g3.x), sc.x, sh.x), 0.f);
            f1 = fmaxf(fmaf(bfhi(g3.x), sc.y, sh.y), 0.f);
            f2 = fmaxf(fmaf(bflo(g3.y), sc.z, sh.z), 0.f);
            f3 = fmaxf(fmaf(bfhi(g3.y), sc.w, sh.w), 0.f);
            b0 += f0; b1 += f1; b2 += f2; b3 += f3;
        } else {
            a0 += bflo(g0.x); a1 += bfhi(g0.x); a2 += bflo(g0.y); a3 += bfhi(g0.y);
            b0 += bflo(g1.x); b1 += bfhi(g1.x); b2 += bflo(g1.y); b3 += bfhi(g1.y);
            a0 += bflo(g2.x); a1 += bfhi(g2.x); a2 += bflo(g2.y); a3 += bfhi(g2.y);
            b0 += bflo(g3.x); b1 += bfhi(g3.x); b2 += bflo(g3.y); b3 += bfhi(g3.y);
        }
    }
    for (; j < end; ++j) {
        int s = srcs[j];
        uint2 g = *(const uint2*)(h + (size_t)s * DIM + c);
        if (bn) {
            a0 += fmaxf(fmaf(bflo(g.x), sc.x, sh.x), 0.f);
            a1 += fmaxf(fmaf(bfhi(g.x), sc.y, sh.y), 0.f);
            a2 += fmaxf(fmaf(bflo(g.y), sc.z, sh.z), 0.f);
            a3 += fmaxf(fmaf(bfhi(g.y), sc.w, sh.w), 0.f);
        } else {
            a0 += bflo(g.x); a1 += bfhi(g.x); a2 += bflo(g.y); a3 += bfhi(g.y);
        }
    }
    float4 r = make_float4(a0 + b0, a1 + b1, a2 + b2, a3 + b3);
    *(float4*)(agg + (size_t)node * DIM + c) = r;
}

// ---------------------------------------------------------------------------
// Split-bf16 MFMA GEMM (near-f32): C = BNrelu(A) @ W + bias.
__global__ void __launch_bounds__(256, 2) k_gemm(
    const float* __restrict__ A, const ushort* __restrict__ Wh,
    const ushort* __restrict__ Wl, const float* __restrict__ bias,
    const float* __restrict__ scale, const float* __restrict__ shift,
    float* __restrict__ Cf, ushort* __restrict__ Cb,
    float* __restrict__ statSum, float* __restrict__ statSq,
    float* __restrict__ outF, int M) {
    __shared__ char smem[65536];
    char* Ah = smem;            // 128 rows x 256B (swizzled) hi plane
    char* Alo = smem + 32768;   // lo plane

    const int t = threadIdx.x;
    const int w = t >> 6;
    const int lane = t & 63;
    const int rquad = lane >> 4;
    const int rcol = lane & 15;
    const int rowBase = blockIdx.x * 128;

    // ---- stage A: f32 load, optional BNrelu, split to bf16 hi/lo ----
#pragma unroll
    for (int i = 0; i < 16; ++i) {
        int idx = t + i * 256;      // 4096 4-float chunks
        int row = idx >> 5;
        int ch = idx & 31;
        int grow = rowBase + row;
        if (grow >= M) grow = M - 1;
        float4 v = *(const float4*)(A + (size_t)grow * DIM + ch * 4);
        if (scale) {
            int c0 = ch * 4;
            v.x = fmaxf(fmaf(v.x, scale[c0 + 0], shift[c0 + 0]), 0.f);
            v.y = fmaxf(fmaf(v.y, scale[c0 + 1], shift[c0 + 1]), 0.f);
            v.z = fmaxf(fmaf(v.z, scale[c0 + 2], shift[c0 + 2]), 0.f);
            v.w = fmaxf(fmaf(v.w, scale[c0 + 3], shift[c0 + 3]), 0.f);
        }
        ushort h0 = f2bf(v.x), h1 = f2bf(v.y), h2 = f2bf(v.z), h3 = f2bf(v.w);
        ushort l0 = f2bf(v.x - bf2f(h0)), l1 = f2bf(v.y - bf2f(h1));
        ushort l2 = f2bf(v.z - bf2f(h2)), l3 = f2bf(v.w - bf2f(h3));
        uint2 hp, lp;
        hp.x = (uint)h0 | ((uint)h1 << 16);
        hp.y = (uint)h2 | ((uint)h3 << 16);
        lp.x = (uint)l0 | ((uint)l1 << 16);
        lp.y = (uint)l2 | ((uint)l3 << 16);
        *(uint2*)(Ah + SWZ(row, row * 256 + ch * 8)) = hp;
        *(uint2*)(Alo + SWZ(row, row * 256 + ch * 8)) = lp;
    }
    __syncthreads();

    // ---- MFMA main loop ----
    f32x4 acc[2][8];
#pragma unroll
    for (int i = 0; i < 2; ++i)
#pragma unroll
        for (int j = 0; j < 8; ++j) acc[i][j] = (f32x4){0.f, 0.f, 0.f, 0.f};

#pragma unroll
    for (int kc = 0; kc < 4; ++kc) {
        bf16x8 bh[8], bl[8];
#pragma unroll
        for (int j = 0; j < 8; ++j) {
            size_t off = (size_t)(j * 16 + rcol) * DIM + kc * 32 + rquad * 8;
            bh[j] = *(const bf16x8*)(Wh + off);
            bl[j] = *(const bf16x8*)(Wl + off);
        }
        int kb = (kc * 32 + rquad * 8) * 2;
        bf16x8 ah[2], al[2];
#pragma unroll
        for (int i = 0; i < 2; ++i) {
            int row = w * 32 + i * 16 + rcol;
            ah[i] = *(const bf16x8*)(Ah + SWZ(row, row * 256 + kb));
            al[i] = *(const bf16x8*)(Alo + SWZ(row, row * 256 + kb));
        }
#pragma unroll
        for (int i = 0; i < 2; ++i)
#pragma unroll
            for (int j = 0; j < 8; ++j) {
                acc[i][j] = __builtin_amdgcn_mfma_f32_16x16x32_bf16(
                    ah[i], bh[j], acc[i][j], 0, 0, 0);
                acc[i][j] = __builtin_amdgcn_mfma_f32_16x16x32_bf16(
                    al[i], bh[j], acc[i][j], 0, 0, 0);
                acc[i][j] = __builtin_amdgcn_mfma_f32_16x16x32_bf16(
                    ah[i], bl[j], acc[i][j], 0, 0, 0);
            }
    }

    // ---- epilogue ----
    float bc[8];
#pragma unroll
    for (int j = 0; j < 8; ++j) bc[j] = bias[j * 16 + rcol];

    if (outF) {  // fused L2 normalize
#pragma unroll
        for (int i = 0; i < 2; ++i) {
#pragma unroll
            for (int r = 0; r < 4; ++r) {
                int row = rowBase + w * 32 + i * 16 + rquad * 4 + r;
                float o[8];
                float ss = 0.f;
#pragma unroll
                for (int j = 0; j < 8; ++j) {
                    o[j] = acc[i][j][r] + bc[j];
                    ss += o[j] * o[j];
                }
                ss += __shfl_xor(ss, 1);
                ss += __shfl_xor(ss, 2);
                ss += __shfl_xor(ss, 4);
                ss += __shfl_xor(ss, 8);
                float inv = 1.f / fmaxf(sqrtf(ss), 1e-12f);
                if (row < M) {
#pragma unroll
                    for (int j = 0; j < 8; ++j)
                        outF[(size_t)row * DIM + j * 16 + rcol] = o[j] * inv;
                }
            }
        }
        return;
    }

    // stats mode: store (f32 or bf16) + column sum/sumsq
    float csum[8], csq[8];
#pragma unroll
    for (int j = 0; j < 8; ++j) { csum[j] = 0.f; csq[j] = 0.f; }
#pragma unroll
    for (int i = 0; i < 2; ++i) {
#pragma unroll
        for (int r = 0; r < 4; ++r) {
            int row = rowBase + w * 32 + i * 16 + rquad * 4 + r;
            if (row < M) {
#pragma unroll
                for (int j = 0; j < 8; ++j) {
                    float o = acc[i][j][r] + bc[j];
                    if (Cf) Cf[(size_t)row * DIM + j * 16 + rcol] = o;
                    else Cb[(size_t)row * DIM + j * 16 + rcol] = f2bf(o);
                    csum[j] += o;
                    csq[j] += o * o;
                }
            }
        }
    }
#pragma unroll
    for (int j = 0; j < 8; ++j) {
        csum[j] += __shfl_xor(csum[j], 16);
        csum[j] += __shfl_xor(csum[j], 32);
        csq[j] += __shfl_xor(csq[j], 16);
        csq[j] += __shfl_xor(csq[j], 32);
    }
    __syncthreads();  // all LDS reads done; reuse for cross-wave reduce
    float* red = (float*)smem;
    if (lane < 16) {
#pragma unroll
        for (int j = 0; j < 8; ++j) {
            red[w * 128 + j * 16 + rcol] = csum[j];
            red[512 + w * 128 + j * 16 + rcol] = csq[j];
        }
    }
    __syncthreads();
    if (t < 128) {
        float s = red[t] + red[128 + t] + red[256 + t] + red[384 + t];
        float q = red[512 + t] + red[640 + t] + red[768 + t] + red[896 + t];
        atomicAdd(statSum + t, s);
        atomicAdd(statSq + t, q);
    }
}

// ---------------------------------------------------------------------------
// Consumes sum/sq -> scale/shift, then ZEROES sum/sq for the next GEMM.
__global__ void k_bnfin(float* __restrict__ sum, float* __restrict__ sq,
                        const float* __restrict__ g,
                        const float* __restrict__ be,
                        float* __restrict__ scale,
                        float* __restrict__ shift, float invN) {
    int c = threadIdx.x;
    float mu = sum[c] * invN;
    float var = sq[c] * invN - mu * mu;
    float inv = rsqrtf(var + 1e-5f);
    float s = g[c] * inv;
    scale[c] = s;
    shift[c] = be[c] - mu * s;
    sum[c] = 0.f;
    sq[c] = 0.f;
}

// ---------------------------------------------------------------------------
extern "C" void kernel_launch(void* const* d_in, const int* in_sizes, int n_in,
                              void* d_out, int out_size, void* d_ws,
                              size_t ws_size, hipStream_t stream) {
    const float* x = (const float*)d_in[0];
    const int* ei = (const int*)d_in[1];
    const float* W1 = (const float*)d_in[2];
    const float* b1 = (const float*)d_in[3];
    const float* g1 = (const float*)d_in[4];
    const float* be1 = (const float*)d_in[5];
    const float* W2 = (const float*)d_in[6];
    const float* b2 = (const float*)d_in[7];
    const float* g_out = (const float*)d_in[8];
    const float* b_out = (const float*)d_in[9];
    float* out = (float*)d_out;

    const int M = M_NODES;
    const int E = N_EDGES_TOT;
    const size_t NM = (size_t)M * DIM;
    const int nChunks = (E + 2047) / 2048;          // 782
    const int nMat = NBKT * nChunks;                // 200192 (multiple of 256)

    float* AGC = (float*)d_ws;         // f32: gather out / GEMM1 in-place out
    ushort* B0 = (ushort*)(AGC + NM);  // bf16 h buffer (gather input)
    ushort* Wh = B0 + NM;              // 6*16384 bf16 hi
    ushort* Wl = Wh + 6 * 16384;       // 6*16384 bf16 lo
    float* st = (float*)(Wl + 6 * 16384);
    float* sum = st;
    float* sq = st + 128;
    float* sc1 = st + 256;
    float* sh1 = st + 384;
    float* sc2 = st + 512;
    float* sh2 = st + 640;
    int2* pairs = (int2*)(st + 768);   // E int2 (8B-aligned: all prior sizes even)
    int* rowptr = (int*)(pairs + E);   // M+1
    int* cntM = rowptr + (M + 2);      // nMat
    int* bsum = cntM + nMat;           // 1024
    int* srcs = bsum + 1024;           // E

    const int* src = ei;
    const int* dst = ei + E;

    const int gemmGrid = (M + 127) / 128;
    const int gathGrid = (M + 7) / 8;
    const float invN = 1.f / (float)M;

    // ---------------- CSR build (bucket radix, no global atomics) ------
    k_bhist<<<nChunks, 256, 0, stream>>>(dst, cntM, E, nChunks);
    k_scanA<<<nMat / 256, 256, 0, stream>>>(cntM, bsum, nMat);
    k_scanB<<<1, 1024, 0, stream>>>(bsum, nMat / 256);
    k_scanC<<<nMat / 256, 256, 0, stream>>>(cntM, bsum);
    k_pairs<<<nChunks, 256, 0, stream>>>(src, dst, cntM, pairs, E, nChunks);
    k_csrD<<<NBKT, 256, 0, stream>>>(pairs, cntM, nChunks, rowptr, srcs, E);

    // ---------------- prep conversions ---------------------------------
    k_cvt<<<(int)((NM / 4 + 255) / 256), 256, 0, stream>>>(x, B0, (int)(NM / 4));
    k_wprep<<<(6 * 16384 + 255) / 256, 256, 0, stream>>>(W1, W2, Wh, Wl);
    k_zerof<<<1, 256, 0, stream>>>(sum, 256);  // sum+sq; bnfin re-zeroes after

    // ---------------- layer 0 ----------------
    k_gather<<<gathGrid, 256, 0, stream>>>(B0, rowptr, srcs, nullptr, nullptr, AGC, M);
    k_gemm<<<gemmGrid, 256, 0, stream>>>(AGC, Wh, Wl, b1, nullptr, nullptr,
                                         AGC, nullptr, sum, sq, nullptr, M);
    k_bnfin<<<1, 128, 0, stream>>>(sum, sq, g1, be1, sc1, sh1, invN);
    k_gemm<<<gemmGrid, 256, 0, stream>>>(AGC, Wh + 3 * 16384, Wl + 3 * 16384, b2,
                                         sc1, sh1, nullptr, B0, sum, sq, nullptr, M);
    k_bnfin<<<1, 128, 0, stream>>>(sum, sq, g_out, b_out, sc2, sh2, invN);

    // ---------------- layer 1 ----------------
    k_gather<<<gathGrid, 256, 0, stream>>>(B0, rowptr, srcs, sc2, sh2, AGC, M);
    k_gemm<<<gemmGrid, 256, 0, stream>>>(AGC, Wh + 16384, Wl + 16384, b1 + 128,
                                         nullptr, nullptr, AGC, nullptr, sum, sq, nullptr, M);
    k_bnfin<<<1, 128, 0, stream>>>(sum, sq, g1 + 128, be1 + 128, sc1, sh1, invN);
    k_gemm<<<gemmGrid, 256, 0, stream>>>(AGC, Wh + 4 * 16384, Wl + 4 * 16384, b2 + 128,
                                         sc1, sh1, nullptr, B0, sum, sq, nullptr, M);
    k_bnfin<<<1, 128, 0, stream>>>(sum, sq, g_out + 128, b_out + 128, sc2, sh2, invN);

    // ---------------- layer 2 ----------------
    k_gather<<<gathGrid, 256, 0, stream>>>(B0, rowptr, srcs, sc2, sh2, AGC, M);
    k_gemm<<<gemmGrid, 256, 0, stream>>>(AGC, Wh + 2 * 16384, Wl + 2 * 16384, b1 + 256,
                                         nullptr, nullptr, AGC, nullptr, sum, sq, nullptr, M);
    k_bnfin<<<1, 128, 0, stream>>>(sum, sq, g1 + 256, be1 + 256, sc1, sh1, invN);
    // final GEMM: fused L2 normalize, f32 straight to d_out
    k_gemm<<<gemmGrid, 256, 0, stream>>>(AGC, Wh + 5 * 16384, Wl + 5 * 16384, b2 + 256,
                                         sc1, sh1, nullptr, nullptr, nullptr, nullptr, out, M);
}